// Round 2
// baseline (28616.293 us; speedup 1.0000x reference)
//
#include <hip/hip_runtime.h>

typedef unsigned short u16;

#define T_STEPS 16
#define NREAL   3328
#define NVIRT   64
#define NTOT    3392
#define HIDD    384
#define FFD     1536
#define NSPARSE 256
#define NDENSE  3072
#define ROWS_ALL (T_STEPS*NTOT)   /* 54272 */
#define NHEAD   8
#define ATT_SCALE 0.14433756729740643f
#define IDSEG   (1<<30)
#define MIDCAP  13568
#define NG      1696              /* track-group size for time attn */

using bf16x8 = __attribute__((ext_vector_type(8))) short;
using f32x4  = __attribute__((ext_vector_type(4))) float;

// ---------------- device helpers ----------------
__device__ __forceinline__ u16 f2b(float f){
  unsigned u = __float_as_uint(f);
  return (u16)((u + 0x7fffu + ((u>>16)&1u)) >> 16);
}
__device__ __forceinline__ void unpack8(uint4 u, float* f){
  f[0]=__uint_as_float(u.x<<16); f[1]=__uint_as_float(u.x&0xffff0000u);
  f[2]=__uint_as_float(u.y<<16); f[3]=__uint_as_float(u.y&0xffff0000u);
  f[4]=__uint_as_float(u.z<<16); f[5]=__uint_as_float(u.z&0xffff0000u);
  f[6]=__uint_as_float(u.w<<16); f[7]=__uint_as_float(u.w&0xffff0000u);
}
__device__ __forceinline__ void load48f(const u16* p, float* f){
#pragma unroll
  for (int c=0;c<6;c++){ uint4 u = *(const uint4*)(p + c*8); unpack8(u, f+c*8); }
}
__device__ __forceinline__ float dot48(const float* q, const u16* p){
  float s = 0.f;
#pragma unroll
  for (int c=0;c<6;c++){
    uint4 u = *(const uint4*)(p + c*8); float kf[8]; unpack8(u,kf);
#pragma unroll
    for (int d=0;d<8;d++) s += q[c*8+d]*kf[d];
  }
  return s;
}
__device__ __forceinline__ void attn_upd(float s, const u16* vp, float& m, float& l, float* acc){
  float mn = fmaxf(m, s);
  float corr = __expf(m - mn);
  float w = __expf(s - mn);
  l = l*corr + w;
#pragma unroll
  for (int c=0;c<6;c++){
    uint4 u = *(const uint4*)(vp + c*8); float vf[8]; unpack8(u,vf);
#pragma unroll
    for (int d=0;d<8;d++){ acc[c*8+d] = acc[c*8+d]*corr + w*vf[d]; }
  }
  m = mn;
}
__device__ __forceinline__ void store48(u16* p, const float* a, float inv){
#pragma unroll
  for (int c=0;c<6;c++){
    uint4 o;
    o.x = (unsigned)f2b(a[c*8+0]*inv) | ((unsigned)f2b(a[c*8+1]*inv)<<16);
    o.y = (unsigned)f2b(a[c*8+2]*inv) | ((unsigned)f2b(a[c*8+3]*inv)<<16);
    o.z = (unsigned)f2b(a[c*8+4]*inv) | ((unsigned)f2b(a[c*8+5]*inv)<<16);
    o.w = (unsigned)f2b(a[c*8+6]*inv) | ((unsigned)f2b(a[c*8+7]*inv)<<16);
    *(uint4*)(p + c*8) = o;
  }
}

// ---------------- GEMM: C[M,N] = A[M,K](bf16) @ Bt[Npad,K]^T (bf16) + bias ----------------
// Row maps: global_row = base + ((r+rofs)/seg)*str + (r+rofs)%seg
template<int OUTF32, int RES, int GELU>
__global__ __launch_bounds__(256) void gemm_mfma(
    const u16* __restrict__ A, int ldA, int aBase, int aRofs, int aSeg, int aStr,
    const u16* __restrict__ Bt, const float* __restrict__ bias,
    void* __restrict__ C, int ldC, int cBase, int cRofs, int cSeg, int cStr,
    int N, int K)
{
  __shared__ __align__(16) u16 As[128][40];
  __shared__ __align__(16) u16 Bs[128][40];
  __shared__ int mapA[128];
  __shared__ int mapC[128];
  int tid = threadIdx.x;
  int bm = blockIdx.x, bn = blockIdx.y;
  if (tid < 128){
    int r = bm*128 + tid + aRofs;
    mapA[tid] = aBase + (r/aSeg)*aStr + r%aSeg;
  } else {
    int t2 = tid - 128;
    int r = bm*128 + t2 + cRofs;
    mapC[t2] = cBase + (r/cSeg)*cStr + r%cSeg;
  }
  int wid = tid>>6, lane = tid&63;
  int wrow = (wid>>1)<<6, wcol = (wid&1)<<6;
  int lr = lane&15, kq = lane>>4;
  f32x4 acc[4][4] = {};
  long nb0 = (long)bn*128;
  for (int k0 = 0; k0 < K; k0 += 32){
    __syncthreads();
#pragma unroll
    for (int it=0; it<2; ++it){
      int idx = tid + it*256;
      int r = idx>>2, cg = (idx&3)<<3;
      uint4 va = *(const uint4*)(A + (long)mapA[r]*ldA + k0 + cg);
      *(uint4*)(&As[r][cg]) = va;
      uint4 vb = *(const uint4*)(Bt + (nb0 + r)*(long)K + k0 + cg);
      *(uint4*)(&Bs[r][cg]) = vb;
    }
    __syncthreads();
    bf16x8 af[4], bfr[4];
#pragma unroll
    for (int mm=0;mm<4;mm++) af[mm]  = *(const bf16x8*)(&As[wrow + mm*16 + lr][kq*8]);
#pragma unroll
    for (int nn=0;nn<4;nn++) bfr[nn] = *(const bf16x8*)(&Bs[wcol + nn*16 + lr][kq*8]);
#pragma unroll
    for (int mm=0;mm<4;mm++){
#pragma unroll
      for (int nn=0;nn<4;nn++){
        acc[mm][nn] = __builtin_amdgcn_mfma_f32_16x16x32_bf16(af[mm], bfr[nn], acc[mm][nn], 0,0,0);
      }
    }
  }
#pragma unroll
  for (int nn=0;nn<4;nn++){
    int col = (int)nb0 + wcol + nn*16 + lr;
    if (col < N){
      float bv = bias[col];
#pragma unroll
      for (int mm=0;mm<4;mm++){
#pragma unroll
        for (int jj=0;jj<4;jj++){
          int rt = wrow + mm*16 + kq*4 + jj;
          float v = acc[mm][nn][jj] + bv;
          if (GELU){
            float x3 = v*v*v;
            v = 0.5f*v*(1.f + tanhf(0.7978845608028654f*(v + 0.044715f*x3)));
          }
          long off = (long)mapC[rt]*ldC + col;
          if (OUTF32){
            float* Cf = (float*)C;
            float r2 = v;
            if (RES) r2 += Cf[off];
            Cf[off] = r2;
          } else {
            ((u16*)C)[off] = f2b(v);
          }
        }
      }
    }
  }
}

// ---------------- LayerNorm over 384, segmented rows, bf16 out, optional affine ----------------
__global__ __launch_bounds__(256) void ln_rows(
    const float* __restrict__ X, u16* __restrict__ H,
    int M, int base, int seg, int str, float eps,
    const float* __restrict__ sc, const float* __restrict__ sh)
{
  int wid = threadIdx.x>>6, lane = threadIdx.x&63;
  int r = blockIdx.x*4 + wid;
  if (r >= M) return;
  long g = base + (long)(r/seg)*str + r%seg;
  const float* xp = X + g*HIDD;
  float v[6]; float s=0.f, ss=0.f;
#pragma unroll
  for (int p=0;p<6;p++){ v[p] = xp[lane + 64*p]; s += v[p]; ss += v[p]*v[p]; }
#pragma unroll
  for (int o=32;o>=1;o>>=1){ s += __shfl_xor(s,o); ss += __shfl_xor(ss,o); }
  float mean = s*(1.f/384.f);
  float var  = ss*(1.f/384.f) - mean*mean;
  float rstd = rsqrtf(var + eps);
  u16* hp = H + g*HIDD;
#pragma unroll
  for (int p=0;p<6;p++){
    int c = lane + 64*p;
    float y = (v[p]-mean)*rstd;
    if (sc) y = y*sc[c] + sh[c];
    hp[c] = f2b(y);
  }
}

// cast f32 rows -> bf16 rows (segmented)
__global__ __launch_bounds__(256) void cast_rows(
    const float* __restrict__ X, u16* __restrict__ H, int M, int base, int seg, int str)
{
  int wid = threadIdx.x>>6, lane = threadIdx.x&63;
  int r = blockIdx.x*4 + wid;
  if (r >= M) return;
  long g = base + (long)(r/seg)*str + r%seg;
  const float* xp = X + g*HIDD;
  u16* hp = H + g*HIDD;
#pragma unroll
  for (int p=0;p<6;p++){ int c = lane + 64*p; hp[c] = f2b(xp[c]); }
}

// elementwise f32 -> bf16
__global__ void cast_arr(const float* __restrict__ S, u16* __restrict__ D, long n){
  long i = (long)blockIdx.x*256 + threadIdx.x;
  if (i < n) D[i] = f2b(S[i]);
}

// broadcast virtual tracks into x
__global__ void set_virt(const float* __restrict__ vtr, float* __restrict__ X){
  int idx = blockIdx.x*256 + threadIdx.x;
  if (idx >= T_STEPS*NVIRT*HIDD) return;
  int c = idx % HIDD;
  int i = (idx / HIDD) % NVIRT;
  int t = idx / (HIDD*NVIRT);
  X[((long)t*NTOT + NREAL + i)*HIDD + c] = vtr[i*HIDD + c];
}

// transpose-cast weights: src + mat*srcStride = [K][N] f32 -> dst[mat] = [Npad][K] bf16 (zero pad)
__global__ void transpose_cast(const float* __restrict__ src, long srcStride,
                               u16* __restrict__ dst, int K, int N, int Npad)
{
  __shared__ float t[32][33];
  int mat = blockIdx.z;
  const float* S = src + (long)mat*srcStride;
  u16* D = dst + (long)mat*Npad*K;
  int k0 = blockIdx.x*32, n0 = blockIdx.y*32;
  int tx = threadIdx.x, ty = threadIdx.y;
#pragma unroll
  for (int yy=0; yy<4; yy++){
    int k = k0+ty+8*yy, n = n0+tx;
    t[ty+8*yy][tx] = (k<K && n<N) ? S[(long)k*N+n] : 0.f;
  }
  __syncthreads();
#pragma unroll
  for (int yy=0; yy<4; yy++){
    int n = n0+ty+8*yy, k = k0+tx;
    if (n<Npad && k<K) D[(long)n*K+k] = f2b(t[tx][ty+8*yy]);
  }
}

// ---------------- attention kernels ----------------
// time self-attn over track group [n0, n0+NG). Q,O global rows; KV compact [t*NG+nl].
// grid (NG/4, 8), block 64
__global__ __launch_bounds__(64) void attn_time_g(const u16* __restrict__ Q, const u16* __restrict__ KV,
                                                  u16* __restrict__ O, int n0){
  int lane = threadIdx.x;
  int nl = blockIdx.x*4 + (lane>>4);
  int tq = lane&15;
  int hh = blockIdx.y;
  long qrow = (long)tq*NTOT + n0 + nl;
  float qv[48]; load48f(Q + qrow*HIDD + hh*48, qv);
  float m=-3e38f, l=0.f, acc[48];
#pragma unroll
  for (int d=0;d<48;d++) acc[d]=0.f;
  for (int tk=0;tk<T_STEPS;tk++){
    long kr = (long)tk*NG + nl;
    const u16* kp = KV + kr*768 + hh*48;
    float s = dot48(qv, kp)*ATT_SCALE;
    attn_upd(s, kp+384, m, l, acc);
  }
  store48(O + qrow*HIDD + hh*48, acc, 1.f/l);
}

// virt self-attn. Q compact [t*64+i], KV compact, O global. grid (16, 8), block 64
__global__ __launch_bounds__(64) void attn_virt(const u16* __restrict__ Q, const u16* __restrict__ KV, u16* __restrict__ O){
  int lane = threadIdx.x;
  int t = blockIdx.x, hh = blockIdx.y;
  long qr = (long)t*NVIRT + lane;
  float qv[48]; load48f(Q + qr*HIDD + hh*48, qv);
  float m=-3e38f, l=0.f, acc[48];
#pragma unroll
  for (int d=0;d<48;d++) acc[d]=0.f;
  for (int tk=0;tk<NVIRT;tk++){
    long kr = (long)t*NVIRT + tk;
    const u16* kp = KV + kr*768 + hh*48;
    float s = dot48(qv, kp)*ATT_SCALE;
    attn_upd(s, kp+384, m, l, acc);
  }
  long orow = (long)t*NTOT + NREAL + lane;
  store48(O + orow*HIDD + hh*48, acc, 1.f/l);
}

// cross: virt queries over real keys, time chunk starting t0 (8 steps).
// Q compact [t*64+i] (all t), KV compact [tl*3328+n], O global. grid (8, 8), block 256
__global__ __launch_bounds__(256) void attn_cross_vr_g(const u16* __restrict__ Q, const u16* __restrict__ KV,
                                                       u16* __restrict__ O, int t0){
  __shared__ float pm[4][64];
  __shared__ float pl[4][64];
  __shared__ float pacc[4][64][48];
  int tl = blockIdx.x, hh = blockIdx.y;
  int w = threadIdx.x>>6, lane = threadIdx.x&63;
  long qr = (long)(t0+tl)*NVIRT + lane;
  float qv[48]; load48f(Q + qr*HIDD + hh*48, qv);
  float m=-3e38f, l=0.f, acc[48];
#pragma unroll
  for (int d=0;d<48;d++) acc[d]=0.f;
  int k0 = w*832, k1 = k0+832;
  for (int mk=k0; mk<k1; ++mk){
    long kr = (long)tl*NREAL + mk;
    const u16* kp = KV + kr*768 + hh*48;
    float s = dot48(qv, kp)*ATT_SCALE;
    attn_upd(s, kp+384, m, l, acc);
  }
  pm[w][lane]=m; pl[w][lane]=l;
#pragma unroll
  for (int d=0;d<48;d++) pacc[w][lane][d]=acc[d];
  __syncthreads();
  if (w==0){
    float M2 = pm[0][lane];
#pragma unroll
    for (int ww=1;ww<4;ww++) M2 = fmaxf(M2, pm[ww][lane]);
    float L=0.f; float out[48];
#pragma unroll
    for (int d=0;d<48;d++) out[d]=0.f;
#pragma unroll
    for (int ww=0;ww<4;ww++){
      float c = __expf(pm[ww][lane]-M2);
      L += pl[ww][lane]*c;
#pragma unroll
      for (int d=0;d<48;d++) out[d] += pacc[ww][lane][d]*c;
    }
    long orow = (long)(t0+tl)*NTOT + NREAL + lane;
    store48(O + orow*HIDD + hh*48, out, 1.f/L);
  }
}

// cross: real queries over virt keys. Q compact [t*3328+n], KV compact [t*64+i], O global.
// grid (52, 16, 8), block 64
__global__ __launch_bounds__(64) void attn_cross_rv(const u16* __restrict__ Q, const u16* __restrict__ KV, u16* __restrict__ O){
  int lane = threadIdx.x;
  int t = blockIdx.y, hh = blockIdx.z;
  int n = blockIdx.x*64 + lane;
  long qr = (long)t*NREAL + n;
  float qv[48]; load48f(Q + qr*HIDD + hh*48, qv);
  float m=-3e38f, l=0.f, acc[48];
#pragma unroll
  for (int d=0;d<48;d++) acc[d]=0.f;
  for (int tk=0;tk<NVIRT;tk++){
    long kr = (long)t*NVIRT + tk;
    const u16* kp = KV + kr*768 + hh*48;
    float s = dot48(qv, kp)*ATT_SCALE;
    attn_upd(s, kp+384, m, l, acc);
  }
  long orow = (long)t*NTOT + n;
  store48(O + orow*HIDD + hh*48, acc, 1.f/l);
}

// local 6x6 windowed self-attn over dense tokens, time chunk t0 (8 steps).
// Q compact [t*3072+d], KV compact [tl*3072+d], O global. grid (88, 8, 8), block 64
__global__ __launch_bounds__(64) void attn_local_g(const u16* __restrict__ Q, const u16* __restrict__ KV,
                                                   u16* __restrict__ O, int t0){
  int lane = threadIdx.x;
  if (lane >= 36) return;
  int wh = blockIdx.x/11, ww = blockIdx.x%11;
  int i = lane/6, jc = lane%6;
  int jmax = (ww==10) ? 4 : 6;
  if (jc >= jmax) return;
  int tl = blockIdx.y, hh = blockIdx.z;
  int d0 = (wh*6+i)*64 + ww*6+jc;
  long qr = (long)(t0+tl)*NDENSE + d0;
  float qv[48]; load48f(Q + qr*HIDD + hh*48, qv);
  float m=-3e38f, l=0.f, acc[48];
#pragma unroll
  for (int dd=0;dd<48;dd++) acc[dd]=0.f;
  for (int i2=0;i2<6;i2++){
    for (int j2=0;j2<jmax;j2++){
      long kr = (long)tl*NDENSE + (wh*6+i2)*64 + ww*6+j2;
      const u16* kp = KV + kr*768 + hh*48;
      float s = dot48(qv, kp)*ATT_SCALE;
      attn_upd(s, kp+384, m, l, acc);
    }
  }
  long orow = (long)(t0+tl)*NTOT + NSPARSE + d0;
  store48(O + orow*HIDD + hh*48, acc, 1.f/l);
}

// ---------------- host ----------------
// per-layer transposed-weight arena offsets (elements)
static const size_t LW_SAQ  = 0;                       // 3 * 147456
static const size_t LW_SAKV = LW_SAQ  + 3ul*147456;    // 3 * 294912
static const size_t LW_SAO  = LW_SAKV + 3ul*294912;    // 3 * 147456
static const size_t LW_SAF1 = LW_SAO  + 3ul*147456;    // 3 * 589824
static const size_t LW_SAF2 = LW_SAF1 + 3ul*589824;    // 3 * 589824
static const size_t LW_CAQ  = LW_SAF2 + 3ul*589824;    // 2 * 147456
static const size_t LW_CAKV = LW_CAQ  + 2ul*147456;    // 2 * 294912
static const size_t LW_CAO  = LW_CAKV + 2ul*294912;    // 2 * 147456
static const size_t LW_CAF1 = LW_CAO  + 2ul*147456;    // 2 * 589824
static const size_t LW_CAF2 = LW_CAF1 + 2ul*589824;    // 2 * 589824
static const size_t LW_TOTAL= LW_CAF2 + 2ul*589824;    // 8,847,360 elems

extern "C" void kernel_launch(void* const* d_in, const int* in_sizes, int n_in,
                              void* d_out, int out_size, void* d_ws, size_t ws_size,
                              hipStream_t stream)
{
  const float* in_t   = (const float*)d_in[0];
  const float* w_in   = (const float*)d_in[2];
  const float* b_in   = (const float*)d_in[3];
  const float* w_out  = (const float*)d_in[4];
  const float* b_out  = (const float*)d_in[5];
  const float* vtr    = (const float*)d_in[6];
  const float* sa_qw  = (const float*)d_in[7];
  const float* sa_qb  = (const float*)d_in[8];
  const float* sa_kvw = (const float*)d_in[9];
  const float* sa_kvb = (const float*)d_in[10];
  const float* sa_ow  = (const float*)d_in[11];
  const float* sa_ob  = (const float*)d_in[12];
  const float* sa_f1w = (const float*)d_in[13];
  const float* sa_f1b = (const float*)d_in[14];
  const float* sa_f2w = (const float*)d_in[15];
  const float* sa_f2b = (const float*)d_in[16];
  const float* ca_qw  = (const float*)d_in[17];
  const float* ca_qb  = (const float*)d_in[18];
  const float* ca_kvw = (const float*)d_in[19];
  const float* ca_kvb = (const float*)d_in[20];
  const float* ca_ow  = (const float*)d_in[21];
  const float* ca_ob  = (const float*)d_in[22];
  const float* ca_f1w = (const float*)d_in[23];
  const float* ca_f1b = (const float*)d_in[24];
  const float* ca_f2w = (const float*)d_in[25];
  const float* ca_f2b = (const float*)d_in[26];
  const float* ca_ncw = (const float*)d_in[27];
  const float* ca_ncb = (const float*)d_in[28];

  char* ws = (char*)d_ws;
  size_t off = 0;
  auto alloc = [&](size_t bytes)->void*{
    void* p = ws + off;
    off += (bytes + 255) & ~(size_t)255;
    return p;
  };
  // ~226 MB total
  float* x  = (float*)alloc((size_t)ROWS_ALL*HIDD*4);   // 83.4 MB  f32 residual stream
  u16* h    = (u16*)alloc((size_t)ROWS_ALL*HIDD*2);     // 41.7 MB  ln output; doubles as attn-O
  u16* qb_  = (u16*)alloc((size_t)ROWS_ALL*HIDD*2);     // 41.7 MB  Q buffer; doubles as MLP mid
  u16* kvb  = (u16*)alloc((size_t)T_STEPS*NG*768*2);    // 41.7 MB  KV (chunked); doubles as input cast
  u16* wt   = (u16*)alloc(LW_TOTAL*2);                  // 17.7 MB  per-layer transposed weights
  u16* mid  = qb_;                                      // MIDCAP*1536*2 == qb_ bytes exactly
  u16* inb  = kvb;                                      // 34.1 MB <= kvb bytes

  auto tcs = [&](const float* src, long srcStride, u16* dst, int K, int Nn, int Npad, int nmat){
    dim3 g((K+31)/32, (Npad+31)/32, nmat), b(32,8);
    transpose_cast<<<g,b,0,stream>>>(src, srcStride, dst, K, Nn, Npad);
  };

  // mode 0=bf16 out, 1=bf16+gelu, 2=f32 out, 3=f32+residual
  auto gemm = [&](int mode, const u16* A, int ldA, int aBase, int aRofs, int aSeg, int aStr,
                  const u16* Bt, const float* bias,
                  void* C, int ldC, int cBase, int cRofs, int cSeg, int cStr,
                  int M, int Nn, int Npad, int K){
    dim3 g(M/128, Npad/128), b(256);
    if (mode==0)      gemm_mfma<0,0,0><<<g,b,0,stream>>>(A,ldA,aBase,aRofs,aSeg,aStr,Bt,bias,C,ldC,cBase,cRofs,cSeg,cStr,Nn,K);
    else if (mode==1) gemm_mfma<0,0,1><<<g,b,0,stream>>>(A,ldA,aBase,aRofs,aSeg,aStr,Bt,bias,C,ldC,cBase,cRofs,cSeg,cStr,Nn,K);
    else if (mode==2) gemm_mfma<1,0,0><<<g,b,0,stream>>>(A,ldA,aBase,aRofs,aSeg,aStr,Bt,bias,C,ldC,cBase,cRofs,cSeg,cStr,Nn,K);
    else              gemm_mfma<1,1,0><<<g,b,0,stream>>>(A,ldA,aBase,aRofs,aSeg,aStr,Bt,bias,C,ldC,cBase,cRofs,cSeg,cStr,Nn,K);
  };
  auto ln = [&](int M, int base, int seg, int str, float eps, const float* sc, const float* sh){
    ln_rows<<<dim3((M+3)/4), dim3(256), 0, stream>>>(x, h, M, base, seg, str, eps, sc, sh);
  };
  auto mlp = [&](int M, int base, int seg, int str,
                 const u16* f1t, const float* f1bias, const u16* f2t, const float* f2bias){
    ln(M, base, seg, str, 1e-6f, nullptr, nullptr);
    for (int r0=0; r0<M; r0+=MIDCAP){
      int Mc = (M-r0 < MIDCAP) ? (M-r0) : MIDCAP;
      gemm(1, h,   HIDD, base, r0, seg, str, f1t, f1bias, mid, FFD, 0, 0, IDSEG, 0, Mc, FFD, FFD, HIDD);
      gemm(3, mid, FFD,  0,    0,  IDSEG, 0, f2t, f2bias, x,  HIDD, base, r0, seg, str, Mc, HIDD, HIDD, FFD);
    }
  };

  // ---- input projection + token assembly ----
  {
    tcs(w_in, 0, wt, 320, 384, 384, 1);
    long nin = (long)T_STEPS*NREAL*320;
    cast_arr<<<dim3((unsigned)((nin+255)/256)), dim3(256), 0, stream>>>(in_t, inb, nin);
    set_virt<<<dim3((T_STEPS*NVIRT*HIDD+255)/256), dim3(256), 0, stream>>>(vtr, x);
    gemm(2, inb, 320, 0,0,IDSEG,0, wt, b_in, x, HIDD, 0,0,NREAL,NTOT, T_STEPS*NREAL, 384, 384, 320);
  }

  // ---- 6 layers ----
  for (int j=0; j<6; ++j){
    // per-layer weight transposes: sa sets 0..2, ca sets 0..1 (slice j of each)
    tcs(sa_qw  + (size_t)j*384*384,  6ul*384*384,  wt+LW_SAQ,  384, 384,  384,  3);
    tcs(sa_kvw + (size_t)j*384*768,  6ul*384*768,  wt+LW_SAKV, 384, 768,  768,  3);
    tcs(sa_ow  + (size_t)j*384*384,  6ul*384*384,  wt+LW_SAO,  384, 384,  384,  3);
    tcs(sa_f1w + (size_t)j*384*1536, 6ul*384*1536, wt+LW_SAF1, 384, 1536, 1536, 3);
    tcs(sa_f2w + (size_t)j*1536*384, 6ul*1536*384, wt+LW_SAF2, 1536,384,  384,  3);
    tcs(ca_qw  + (size_t)j*384*384,  6ul*384*384,  wt+LW_CAQ,  384, 384,  384,  2);
    tcs(ca_kvw + (size_t)j*384*768,  6ul*384*768,  wt+LW_CAKV, 384, 768,  768,  2);
    tcs(ca_ow  + (size_t)j*384*384,  6ul*384*384,  wt+LW_CAO,  384, 384,  384,  2);
    tcs(ca_f1w + (size_t)j*384*1536, 6ul*384*1536, wt+LW_CAF1, 384, 1536, 1536, 2);
    tcs(ca_f2w + (size_t)j*1536*384, 6ul*1536*384, wt+LW_CAF2, 1536,384,  384,  2);

    // ===== self over time (all tokens), kv chunked by 2 track groups =====
    {
      int sl = 0*6 + j;
      ln(ROWS_ALL, 0, IDSEG, 0, 1e-6f, nullptr, nullptr);
      gemm(0, h, HIDD, 0,0,IDSEG,0, wt+LW_SAQ, sa_qb+sl*384, qb_, HIDD, 0,0,IDSEG,0, ROWS_ALL, 384,384,384);
      for (int g2=0; g2<2; ++g2){
        int n0 = g2*NG;
        gemm(0, h, HIDD, n0,0,NG,NTOT, wt+LW_SAKV, sa_kvb+sl*768, kvb, 768, 0,0,IDSEG,0, T_STEPS*NG, 768,768,384);
        attn_time_g<<<dim3(NG/4, NHEAD), 64, 0, stream>>>(qb_, kvb, h, n0);
      }
      gemm(3, h, HIDD, 0,0,IDSEG,0, wt+LW_SAO, sa_ob+sl*384, x, HIDD, 0,0,IDSEG,0, ROWS_ALL, 384,384,384);
      mlp(ROWS_ALL, 0, IDSEG, 0, wt+LW_SAF1, sa_f1b+sl*1536, wt+LW_SAF2, sa_f2b+sl*384);
    }

    // ===== cross: virt queries <- real context, kv chunked by 2 time halves =====
    {
      int cl = 0*6 + j;
      ln(T_STEPS*NVIRT, NREAL, NVIRT, NTOT, 1e-6f, nullptr, nullptr);
      ln(T_STEPS*NREAL, 0, NREAL, NTOT, 1e-5f, ca_ncw+cl*384, ca_ncb+cl*384);
      gemm(0, h, HIDD, NREAL,0,NVIRT,NTOT, wt+LW_CAQ, ca_qb+cl*384, qb_, HIDD, 0,0,IDSEG,0, T_STEPS*NVIRT, 384,384,384);
      for (int tc=0; tc<T_STEPS; tc+=8){
        gemm(0, h, HIDD, tc*NTOT,0,NREAL,NTOT, wt+LW_CAKV, ca_kvb+cl*768, kvb, 768, 0,0,IDSEG,0, 8*NREAL, 768,768,384);
        attn_cross_vr_g<<<dim3(8, NHEAD), 256, 0, stream>>>(qb_, kvb, h, tc);
      }
      gemm(3, h, HIDD, NREAL,0,NVIRT,NTOT, wt+LW_CAO, ca_ob+cl*384, x, HIDD, NREAL,0,NVIRT,NTOT, T_STEPS*NVIRT, 384,384,384);
      mlp(T_STEPS*NVIRT, NREAL, NVIRT, NTOT, wt+LW_CAF1, ca_f1b+cl*1536, wt+LW_CAF2, ca_f2b+cl*384);
    }

    // ===== self over virt tokens =====
    {
      int sl = 1*6 + j;
      ln(T_STEPS*NVIRT, NREAL, NVIRT, NTOT, 1e-6f, nullptr, nullptr);
      gemm(0, h, HIDD, NREAL,0,NVIRT,NTOT, wt+LW_SAQ+1ul*147456, sa_qb+sl*384, qb_, HIDD, 0,0,IDSEG,0, T_STEPS*NVIRT, 384,384,384);
      gemm(0, h, HIDD, NREAL,0,NVIRT,NTOT, wt+LW_SAKV+1ul*294912, sa_kvb+sl*768, kvb, 768, 0,0,IDSEG,0, T_STEPS*NVIRT, 768,768,384);
      attn_virt<<<dim3(T_STEPS, NHEAD), 64, 0, stream>>>(qb_, kvb, h);
      gemm(3, h, HIDD, NREAL,0,NVIRT,NTOT, wt+LW_SAO+1ul*147456, sa_ob+sl*384, x, HIDD, NREAL,0,NVIRT,NTOT, T_STEPS*NVIRT, 384,384,384);
      mlp(T_STEPS*NVIRT, NREAL, NVIRT, NTOT, wt+LW_SAF1+1ul*589824, sa_f1b+sl*1536, wt+LW_SAF2+1ul*589824, sa_f2b+sl*384);
    }

    // ===== local windowed self over dense tokens, kv chunked by 2 time halves =====
    {
      int sl = 2*6 + j;
      ln(T_STEPS*NDENSE, NSPARSE, NDENSE, NTOT, 1e-6f, nullptr, nullptr);
      gemm(0, h, HIDD, NSPARSE,0,NDENSE,NTOT, wt+LW_SAQ+2ul*147456, sa_qb+sl*384, qb_, HIDD, 0,0,IDSEG,0, T_STEPS*NDENSE, 384,384,384);
      for (int tc=0; tc<T_STEPS; tc+=8){
        gemm(0, h, HIDD, tc*NTOT+NSPARSE,0,NDENSE,NTOT, wt+LW_SAKV+2ul*294912, sa_kvb+sl*768, kvb, 768, 0,0,IDSEG,0, 8*NDENSE, 768,768,384);
        attn_local_g<<<dim3(88, 8, NHEAD), 64, 0, stream>>>(qb_, kvb, h, tc);
      }
      gemm(3, h, HIDD, NSPARSE,0,NDENSE,NTOT, wt+LW_SAO+2ul*147456, sa_ob+sl*384, x, HIDD, NSPARSE,0,NDENSE,NTOT, T_STEPS*NDENSE, 384,384,384);
      mlp(T_STEPS*NDENSE, NSPARSE, NDENSE, NTOT, wt+LW_SAF1+2ul*589824, sa_f1b+sl*1536, wt+LW_SAF2+2ul*589824, sa_f2b+sl*384);
    }

    // ===== cross: real queries <- virt context =====
    {
      int cl = 1*6 + j;
      ln(T_STEPS*NREAL, 0, NREAL, NTOT, 1e-6f, nullptr, nullptr);
      ln(T_STEPS*NVIRT, NREAL, NVIRT, NTOT, 1e-5f, ca_ncw+cl*384, ca_ncb+cl*384);
      gemm(0, h, HIDD, NREAL,0,NVIRT,NTOT, wt+LW_CAKV+1ul*294912, ca_kvb+cl*768, kvb, 768, 0,0,IDSEG,0, T_STEPS*NVIRT, 768,768,384);
      gemm(0, h, HIDD, 0,0,NREAL,NTOT, wt+LW_CAQ+1ul*147456, ca_qb+cl*384, qb_, HIDD, 0,0,IDSEG,0, T_STEPS*NREAL, 384,384,384);
      attn_cross_rv<<<dim3(52, T_STEPS, NHEAD), 64, 0, stream>>>(qb_, kvb, h);
      gemm(3, h, HIDD, 0,0,NREAL,NTOT, wt+LW_CAO+1ul*147456, ca_ob+cl*384, x, HIDD, 0,0,NREAL,NTOT, T_STEPS*NREAL, 384,384,384);
      mlp(T_STEPS*NREAL, 0, NREAL, NTOT, wt+LW_CAF1+1ul*589824, ca_f1b+cl*1536, wt+LW_CAF2+1ul*589824, ca_f2b+cl*384);
    }
  }

  // ---- output projection ----
  tcs(w_out, 0, wt, 384, 130, 256, 1);
  cast_rows<<<dim3((T_STEPS*NREAL+3)/4), dim3(256), 0, stream>>>(x, h, T_STEPS*NREAL, 0, NREAL, NTOT);
  gemm(2, h, HIDD, 0,0,NREAL,NTOT, wt, b_out, d_out, 130, 0,0,IDSEG,0, T_STEPS*NREAL, 130, 256, 384);
}

// Round 3
// 28109.177 us; speedup vs baseline: 1.0180x; 1.0180x over previous
//
#include <hip/hip_runtime.h>

typedef unsigned short u16;

#define T_STEPS 16
#define NREAL   3328
#define NVIRT   64
#define NTOT    3392
#define HIDD    384
#define FFD     1536
#define NSPARSE 256
#define NDENSE  3072
#define ROWS_ALL (T_STEPS*NTOT)   /* 54272 */
#define NHEAD   8
#define ATT_SCALE 0.14433756729740643f
#define IDSEG   (1<<30)
#define MIDCAP  13568
#define NG      1696              /* track-group size for time attn */

using bf16x8 = __attribute__((ext_vector_type(8))) short;
using f32x4  = __attribute__((ext_vector_type(4))) float;

// ---------------- device helpers ----------------
__device__ __forceinline__ u16 f2b(float f){
  unsigned u = __float_as_uint(f);
  return (u16)((u + 0x7fffu + ((u>>16)&1u)) >> 16);
}
__device__ __forceinline__ void unpack8(uint4 u, float* f){
  f[0]=__uint_as_float(u.x<<16); f[1]=__uint_as_float(u.x&0xffff0000u);
  f[2]=__uint_as_float(u.y<<16); f[3]=__uint_as_float(u.y&0xffff0000u);
  f[4]=__uint_as_float(u.z<<16); f[5]=__uint_as_float(u.z&0xffff0000u);
  f[6]=__uint_as_float(u.w<<16); f[7]=__uint_as_float(u.w&0xffff0000u);
}
__device__ __forceinline__ void load48f(const u16* p, float* f){
#pragma unroll
  for (int c=0;c<6;c++){ uint4 u = *(const uint4*)(p + c*8); unpack8(u, f+c*8); }
}
__device__ __forceinline__ float dot48(const float* q, const u16* p){
  float s = 0.f;
#pragma unroll
  for (int c=0;c<6;c++){
    uint4 u = *(const uint4*)(p + c*8); float kf[8]; unpack8(u,kf);
#pragma unroll
    for (int d=0;d<8;d++) s += q[c*8+d]*kf[d];
  }
  return s;
}
__device__ __forceinline__ void attn_upd(float s, const u16* vp, float& m, float& l, float* acc){
  float mn = fmaxf(m, s);
  float corr = __expf(m - mn);
  float w = __expf(s - mn);
  l = l*corr + w;
#pragma unroll
  for (int c=0;c<6;c++){
    uint4 u = *(const uint4*)(vp + c*8); float vf[8]; unpack8(u,vf);
#pragma unroll
    for (int d=0;d<8;d++){ acc[c*8+d] = acc[c*8+d]*corr + w*vf[d]; }
  }
  m = mn;
}
__device__ __forceinline__ void store48(u16* p, const float* a, float inv){
#pragma unroll
  for (int c=0;c<6;c++){
    uint4 o;
    o.x = (unsigned)f2b(a[c*8+0]*inv) | ((unsigned)f2b(a[c*8+1]*inv)<<16);
    o.y = (unsigned)f2b(a[c*8+2]*inv) | ((unsigned)f2b(a[c*8+3]*inv)<<16);
    o.z = (unsigned)f2b(a[c*8+4]*inv) | ((unsigned)f2b(a[c*8+5]*inv)<<16);
    o.w = (unsigned)f2b(a[c*8+6]*inv) | ((unsigned)f2b(a[c*8+7]*inv)<<16);
    *(uint4*)(p + c*8) = o;
  }
}

// async global->LDS, 16 bytes per lane; lds dest must be wave-uniform base (lane*16 auto)
__device__ __forceinline__ void gload16(const u16* g, u16* l){
  __builtin_amdgcn_global_load_lds((const __attribute__((address_space(1))) void*)g,
                                   (__attribute__((address_space(3))) void*)l, 16, 0, 0);
}

// ---------------- GEMM: C[M,N] = A[M,K](bf16) @ Bt[Npad,K]^T (bf16) + bias ----------------
// Row maps: global_row = base + ((r+rofs)/seg)*str + (r+rofs)%seg
// m97 structure: 128x128 tile, BK=32, linear LDS [128][32], global_load_lds dwordx4 staging.
template<int OUTF32, int RES, int GELU>
__global__ __launch_bounds__(256) void gemm_mfma(
    const u16* __restrict__ A, int ldA, int aBase, int aRofs, int aSeg, int aStr,
    const u16* __restrict__ Bt, const float* __restrict__ bias,
    void* __restrict__ C, int ldC, int cBase, int cRofs, int cSeg, int cStr,
    int N, int K)
{
  __shared__ __align__(16) u16 As[128*32];
  __shared__ __align__(16) u16 Bs[128*32];
  __shared__ int mapA[128];
  __shared__ int mapC[128];
  int tid = threadIdx.x;
  int bm = blockIdx.x, bn = blockIdx.y;
  if (tid < 128){
    int r = bm*128 + tid + aRofs;
    mapA[tid] = aBase + (r/aSeg)*aStr + r%aSeg;
  } else {
    int t2 = tid - 128;
    int r = bm*128 + t2 + cRofs;
    mapC[t2] = cBase + (r/cSeg)*cStr + r%cSeg;
  }
  __syncthreads();

  int wid = tid>>6, lane = tid&63;
  // staging: wave wid owns rows [wid*32, wid*32+32) of both tiles.
  // lane covers row srow(+16) col (lane&3)*8 — matches linear LDS order (4 lanes/row, 16B each)
  int srow = (wid<<5) + (lane>>2);
  int scol = (lane&3)<<3;
  const u16* aSrc0 = A + (long)mapA[srow]*ldA + scol;
  const u16* aSrc1 = A + (long)mapA[srow+16]*ldA + scol;
  long nb0 = (long)bn*128;
  const u16* bSrc0 = Bt + (nb0 + srow)*(long)K + scol;
  const u16* bSrc1 = Bt + (nb0 + srow + 16)*(long)K + scol;
  u16* aDst0 = As + (wid<<5)*32;           // wave-uniform
  u16* aDst1 = As + ((wid<<5)+16)*32;
  u16* bDst0 = Bs + (wid<<5)*32;
  u16* bDst1 = Bs + ((wid<<5)+16)*32;

  int wrow = (wid>>1)<<6, wcol = (wid&1)<<6;
  int lr = lane&15, kq = lane>>4;
  f32x4 acc[4][4] = {};
  for (int k0 = 0; k0 < K; k0 += 32){
    gload16(aSrc0 + k0, aDst0);
    gload16(aSrc1 + k0, aDst1);
    gload16(bSrc0 + k0, bDst0);
    gload16(bSrc1 + k0, bDst1);
    __syncthreads();     // compiler drains vmcnt before barrier -> LDS ready
    bf16x8 af[4], bfr[4];
#pragma unroll
    for (int mm=0;mm<4;mm++) af[mm]  = *(const bf16x8*)(As + (wrow + mm*16 + lr)*32 + kq*8);
#pragma unroll
    for (int nn=0;nn<4;nn++) bfr[nn] = *(const bf16x8*)(Bs + (wcol + nn*16 + lr)*32 + kq*8);
#pragma unroll
    for (int mm=0;mm<4;mm++){
#pragma unroll
      for (int nn=0;nn<4;nn++){
        acc[mm][nn] = __builtin_amdgcn_mfma_f32_16x16x32_bf16(af[mm], bfr[nn], acc[mm][nn], 0,0,0);
      }
    }
    __syncthreads();     // compute done before next stage overwrites
  }
#pragma unroll
  for (int nn=0;nn<4;nn++){
    int col = (int)nb0 + wcol + nn*16 + lr;
    if (col < N){
      float bv = bias[col];
#pragma unroll
      for (int mm=0;mm<4;mm++){
#pragma unroll
        for (int jj=0;jj<4;jj++){
          int rt = wrow + mm*16 + kq*4 + jj;
          float v = acc[mm][nn][jj] + bv;
          if (GELU){
            float x3 = v*v*v;
            v = 0.5f*v*(1.f + tanhf(0.7978845608028654f*(v + 0.044715f*x3)));
          }
          long off = (long)mapC[rt]*ldC + col;
          if (OUTF32){
            float* Cf = (float*)C;
            float r2 = v;
            if (RES) r2 += Cf[off];
            Cf[off] = r2;
          } else {
            ((u16*)C)[off] = f2b(v);
          }
        }
      }
    }
  }
}

// ---------------- LayerNorm over 384, segmented rows, bf16 out, optional affine ----------------
__global__ __launch_bounds__(256) void ln_rows(
    const float* __restrict__ X, u16* __restrict__ H,
    int M, int base, int seg, int str, float eps,
    const float* __restrict__ sc, const float* __restrict__ sh)
{
  int wid = threadIdx.x>>6, lane = threadIdx.x&63;
  int r = blockIdx.x*4 + wid;
  if (r >= M) return;
  long g = base + (long)(r/seg)*str + r%seg;
  const float* xp = X + g*HIDD;
  float v[6]; float s=0.f, ss=0.f;
#pragma unroll
  for (int p=0;p<6;p++){ v[p] = xp[lane + 64*p]; s += v[p]; ss += v[p]*v[p]; }
#pragma unroll
  for (int o=32;o>=1;o>>=1){ s += __shfl_xor(s,o); ss += __shfl_xor(ss,o); }
  float mean = s*(1.f/384.f);
  float var  = ss*(1.f/384.f) - mean*mean;
  float rstd = rsqrtf(var + eps);
  u16* hp = H + g*HIDD;
#pragma unroll
  for (int p=0;p<6;p++){
    int c = lane + 64*p;
    float y = (v[p]-mean)*rstd;
    if (sc) y = y*sc[c] + sh[c];
    hp[c] = f2b(y);
  }
}

// cast f32 rows -> bf16 rows (segmented)
__global__ __launch_bounds__(256) void cast_rows(
    const float* __restrict__ X, u16* __restrict__ H, int M, int base, int seg, int str)
{
  int wid = threadIdx.x>>6, lane = threadIdx.x&63;
  int r = blockIdx.x*4 + wid;
  if (r >= M) return;
  long g = base + (long)(r/seg)*str + r%seg;
  const float* xp = X + g*HIDD;
  u16* hp = H + g*HIDD;
#pragma unroll
  for (int p=0;p<6;p++){ int c = lane + 64*p; hp[c] = f2b(xp[c]); }
}

// elementwise f32 -> bf16
__global__ void cast_arr(const float* __restrict__ S, u16* __restrict__ D, long n){
  long i = (long)blockIdx.x*256 + threadIdx.x;
  if (i < n) D[i] = f2b(S[i]);
}

// broadcast virtual tracks into x
__global__ void set_virt(const float* __restrict__ vtr, float* __restrict__ X){
  int idx = blockIdx.x*256 + threadIdx.x;
  if (idx >= T_STEPS*NVIRT*HIDD) return;
  int c = idx % HIDD;
  int i = (idx / HIDD) % NVIRT;
  int t = idx / (HIDD*NVIRT);
  X[((long)t*NTOT + NREAL + i)*HIDD + c] = vtr[i*HIDD + c];
}

// transpose-cast weights: src + mat*srcStride = [K][N] f32 -> dst[mat] = [Npad][K] bf16 (zero pad)
__global__ void transpose_cast(const float* __restrict__ src, long srcStride,
                               u16* __restrict__ dst, int K, int N, int Npad)
{
  __shared__ float t[32][33];
  int mat = blockIdx.z;
  const float* S = src + (long)mat*srcStride;
  u16* D = dst + (long)mat*Npad*K;
  int k0 = blockIdx.x*32, n0 = blockIdx.y*32;
  int tx = threadIdx.x, ty = threadIdx.y;
#pragma unroll
  for (int yy=0; yy<4; yy++){
    int k = k0+ty+8*yy, n = n0+tx;
    t[ty+8*yy][tx] = (k<K && n<N) ? S[(long)k*N+n] : 0.f;
  }
  __syncthreads();
#pragma unroll
  for (int yy=0; yy<4; yy++){
    int n = n0+ty+8*yy, k = k0+tx;
    if (n<Npad && k<K) D[(long)n*K+k] = f2b(t[tx][ty+8*yy]);
  }
}

// ---------------- attention kernels ----------------
// time self-attn over track group [n0, n0+NG). Q,O global rows; KV compact [t*NG+nl].
// grid (NG/4, 8), block 64
__global__ __launch_bounds__(64) void attn_time_g(const u16* __restrict__ Q, const u16* __restrict__ KV,
                                                  u16* __restrict__ O, int n0){
  int lane = threadIdx.x;
  int nl = blockIdx.x*4 + (lane>>4);
  int tq = lane&15;
  int hh = blockIdx.y;
  long qrow = (long)tq*NTOT + n0 + nl;
  float qv[48]; load48f(Q + qrow*HIDD + hh*48, qv);
  float m=-3e38f, l=0.f, acc[48];
#pragma unroll
  for (int d=0;d<48;d++) acc[d]=0.f;
  for (int tk=0;tk<T_STEPS;tk++){
    long kr = (long)tk*NG + nl;
    const u16* kp = KV + kr*768 + hh*48;
    float s = dot48(qv, kp)*ATT_SCALE;
    attn_upd(s, kp+384, m, l, acc);
  }
  store48(O + qrow*HIDD + hh*48, acc, 1.f/l);
}

// virt self-attn. Q compact [t*64+i], KV compact, O global. grid (16, 8), block 64
__global__ __launch_bounds__(64) void attn_virt(const u16* __restrict__ Q, const u16* __restrict__ KV, u16* __restrict__ O){
  int lane = threadIdx.x;
  int t = blockIdx.x, hh = blockIdx.y;
  long qr = (long)t*NVIRT + lane;
  float qv[48]; load48f(Q + qr*HIDD + hh*48, qv);
  float m=-3e38f, l=0.f, acc[48];
#pragma unroll
  for (int d=0;d<48;d++) acc[d]=0.f;
  for (int tk=0;tk<NVIRT;tk++){
    long kr = (long)t*NVIRT + tk;
    const u16* kp = KV + kr*768 + hh*48;
    float s = dot48(qv, kp)*ATT_SCALE;
    attn_upd(s, kp+384, m, l, acc);
  }
  long orow = (long)t*NTOT + NREAL + lane;
  store48(O + orow*HIDD + hh*48, acc, 1.f/l);
}

// cross: virt queries over real keys, time chunk starting t0 (8 steps).
// Q compact [t*64+i] (all t), KV compact [tl*3328+n], O global. grid (8, 8), block 256
__global__ __launch_bounds__(256) void attn_cross_vr_g(const u16* __restrict__ Q, const u16* __restrict__ KV,
                                                       u16* __restrict__ O, int t0){
  __shared__ float pm[4][64];
  __shared__ float pl[4][64];
  __shared__ float pacc[4][64][48];
  int tl = blockIdx.x, hh = blockIdx.y;
  int w = threadIdx.x>>6, lane = threadIdx.x&63;
  long qr = (long)(t0+tl)*NVIRT + lane;
  float qv[48]; load48f(Q + qr*HIDD + hh*48, qv);
  float m=-3e38f, l=0.f, acc[48];
#pragma unroll
  for (int d=0;d<48;d++) acc[d]=0.f;
  int k0 = w*832, k1 = k0+832;
  for (int mk=k0; mk<k1; ++mk){
    long kr = (long)tl*NREAL + mk;
    const u16* kp = KV + kr*768 + hh*48;
    float s = dot48(qv, kp)*ATT_SCALE;
    attn_upd(s, kp+384, m, l, acc);
  }
  pm[w][lane]=m; pl[w][lane]=l;
#pragma unroll
  for (int d=0;d<48;d++) pacc[w][lane][d]=acc[d];
  __syncthreads();
  if (w==0){
    float M2 = pm[0][lane];
#pragma unroll
    for (int ww=1;ww<4;ww++) M2 = fmaxf(M2, pm[ww][lane]);
    float L=0.f; float out[48];
#pragma unroll
    for (int d=0;d<48;d++) out[d]=0.f;
#pragma unroll
    for (int ww=0;ww<4;ww++){
      float c = __expf(pm[ww][lane]-M2);
      L += pl[ww][lane]*c;
#pragma unroll
      for (int d=0;d<48;d++) out[d] += pacc[ww][lane][d]*c;
    }
    long orow = (long)(t0+tl)*NTOT + NREAL + lane;
    store48(O + orow*HIDD + hh*48, out, 1.f/L);
  }
}

// cross: real queries over virt keys. Q compact [t*3328+n], KV compact [t*64+i], O global.
// grid (52, 16, 8), block 64
__global__ __launch_bounds__(64) void attn_cross_rv(const u16* __restrict__ Q, const u16* __restrict__ KV, u16* __restrict__ O){
  int lane = threadIdx.x;
  int t = blockIdx.y, hh = blockIdx.z;
  int n = blockIdx.x*64 + lane;
  long qr = (long)t*NREAL + n;
  float qv[48]; load48f(Q + qr*HIDD + hh*48, qv);
  float m=-3e38f, l=0.f, acc[48];
#pragma unroll
  for (int d=0;d<48;d++) acc[d]=0.f;
  for (int tk=0;tk<NVIRT;tk++){
    long kr = (long)t*NVIRT + tk;
    const u16* kp = KV + kr*768 + hh*48;
    float s = dot48(qv, kp)*ATT_SCALE;
    attn_upd(s, kp+384, m, l, acc);
  }
  long orow = (long)t*NTOT + n;
  store48(O + orow*HIDD + hh*48, acc, 1.f/l);
}

// local 6x6 windowed self-attn over dense tokens, time chunk t0 (8 steps).
// Q compact [t*3072+d], KV compact [tl*3072+d], O global. grid (88, 8, 8), block 64
__global__ __launch_bounds__(64) void attn_local_g(const u16* __restrict__ Q, const u16* __restrict__ KV,
                                                   u16* __restrict__ O, int t0){
  int lane = threadIdx.x;
  if (lane >= 36) return;
  int wh = blockIdx.x/11, ww = blockIdx.x%11;
  int i = lane/6, jc = lane%6;
  int jmax = (ww==10) ? 4 : 6;
  if (jc >= jmax) return;
  int tl = blockIdx.y, hh = blockIdx.z;
  int d0 = (wh*6+i)*64 + ww*6+jc;
  long qr = (long)(t0+tl)*NDENSE + d0;
  float qv[48]; load48f(Q + qr*HIDD + hh*48, qv);
  float m=-3e38f, l=0.f, acc[48];
#pragma unroll
  for (int dd=0;dd<48;dd++) acc[dd]=0.f;
  for (int i2=0;i2<6;i2++){
    for (int j2=0;j2<jmax;j2++){
      long kr = (long)tl*NDENSE + (wh*6+i2)*64 + ww*6+j2;
      const u16* kp = KV + kr*768 + hh*48;
      float s = dot48(qv, kp)*ATT_SCALE;
      attn_upd(s, kp+384, m, l, acc);
    }
  }
  long orow = (long)(t0+tl)*NTOT + NSPARSE + d0;
  store48(O + orow*HIDD + hh*48, acc, 1.f/l);
}

// ---------------- host ----------------
// per-layer transposed-weight arena offsets (elements)
static const size_t LW_SAQ  = 0;                       // 3 * 147456
static const size_t LW_SAKV = LW_SAQ  + 3ul*147456;    // 3 * 294912
static const size_t LW_SAO  = LW_SAKV + 3ul*294912;    // 3 * 147456
static const size_t LW_SAF1 = LW_SAO  + 3ul*147456;    // 3 * 589824
static const size_t LW_SAF2 = LW_SAF1 + 3ul*589824;    // 3 * 589824
static const size_t LW_CAQ  = LW_SAF2 + 3ul*589824;    // 2 * 147456
static const size_t LW_CAKV = LW_CAQ  + 2ul*147456;    // 2 * 294912
static const size_t LW_CAO  = LW_CAKV + 2ul*294912;    // 2 * 147456
static const size_t LW_CAF1 = LW_CAO  + 2ul*147456;    // 2 * 589824
static const size_t LW_CAF2 = LW_CAF1 + 2ul*589824;    // 2 * 589824
static const size_t LW_TOTAL= LW_CAF2 + 2ul*589824;    // 8,847,360 elems

extern "C" void kernel_launch(void* const* d_in, const int* in_sizes, int n_in,
                              void* d_out, int out_size, void* d_ws, size_t ws_size,
                              hipStream_t stream)
{
  const float* in_t   = (const float*)d_in[0];
  const float* w_in   = (const float*)d_in[2];
  const float* b_in   = (const float*)d_in[3];
  const float* w_out  = (const float*)d_in[4];
  const float* b_out  = (const float*)d_in[5];
  const float* vtr    = (const float*)d_in[6];
  const float* sa_qw  = (const float*)d_in[7];
  const float* sa_qb  = (const float*)d_in[8];
  const float* sa_kvw = (const float*)d_in[9];
  const float* sa_kvb = (const float*)d_in[10];
  const float* sa_ow  = (const float*)d_in[11];
  const float* sa_ob  = (const float*)d_in[12];
  const float* sa_f1w = (const float*)d_in[13];
  const float* sa_f1b = (const float*)d_in[14];
  const float* sa_f2w = (const float*)d_in[15];
  const float* sa_f2b = (const float*)d_in[16];
  const float* ca_qw  = (const float*)d_in[17];
  const float* ca_qb  = (const float*)d_in[18];
  const float* ca_kvw = (const float*)d_in[19];
  const float* ca_kvb = (const float*)d_in[20];
  const float* ca_ow  = (const float*)d_in[21];
  const float* ca_ob  = (const float*)d_in[22];
  const float* ca_f1w = (const float*)d_in[23];
  const float* ca_f1b = (const float*)d_in[24];
  const float* ca_f2w = (const float*)d_in[25];
  const float* ca_f2b = (const float*)d_in[26];
  const float* ca_ncw = (const float*)d_in[27];
  const float* ca_ncb = (const float*)d_in[28];

  char* ws = (char*)d_ws;
  size_t off = 0;
  auto alloc = [&](size_t bytes)->void*{
    void* p = ws + off;
    off += (bytes + 255) & ~(size_t)255;
    return p;
  };
  // ~226 MB total
  float* x  = (float*)alloc((size_t)ROWS_ALL*HIDD*4);   // 83.4 MB  f32 residual stream
  u16* h    = (u16*)alloc((size_t)ROWS_ALL*HIDD*2);     // 41.7 MB  ln output; doubles as attn-O
  u16* qb_  = (u16*)alloc((size_t)ROWS_ALL*HIDD*2);     // 41.7 MB  Q buffer; doubles as MLP mid
  u16* kvb  = (u16*)alloc((size_t)T_STEPS*NG*768*2);    // 41.7 MB  KV (chunked); doubles as input cast
  u16* wt   = (u16*)alloc(LW_TOTAL*2);                  // 17.7 MB  per-layer transposed weights
  u16* mid  = qb_;                                      // MIDCAP*1536*2 == qb_ bytes exactly
  u16* inb  = kvb;                                      // 34.1 MB <= kvb bytes

  auto tcs = [&](const float* src, long srcStride, u16* dst, int K, int Nn, int Npad, int nmat){
    dim3 g((K+31)/32, (Npad+31)/32, nmat), b(32,8);
    transpose_cast<<<g,b,0,stream>>>(src, srcStride, dst, K, Nn, Npad);
  };

  // mode 0=bf16 out, 1=bf16+gelu, 2=f32 out, 3=f32+residual
  auto gemm = [&](int mode, const u16* A, int ldA, int aBase, int aRofs, int aSeg, int aStr,
                  const u16* Bt, const float* bias,
                  void* C, int ldC, int cBase, int cRofs, int cSeg, int cStr,
                  int M, int Nn, int Npad, int K){
    dim3 g(M/128, Npad/128), b(256);
    if (mode==0)      gemm_mfma<0,0,0><<<g,b,0,stream>>>(A,ldA,aBase,aRofs,aSeg,aStr,Bt,bias,C,ldC,cBase,cRofs,cSeg,cStr,Nn,K);
    else if (mode==1) gemm_mfma<0,0,1><<<g,b,0,stream>>>(A,ldA,aBase,aRofs,aSeg,aStr,Bt,bias,C,ldC,cBase,cRofs,cSeg,cStr,Nn,K);
    else if (mode==2) gemm_mfma<1,0,0><<<g,b,0,stream>>>(A,ldA,aBase,aRofs,aSeg,aStr,Bt,bias,C,ldC,cBase,cRofs,cSeg,cStr,Nn,K);
    else              gemm_mfma<1,1,0><<<g,b,0,stream>>>(A,ldA,aBase,aRofs,aSeg,aStr,Bt,bias,C,ldC,cBase,cRofs,cSeg,cStr,Nn,K);
  };
  auto ln = [&](int M, int base, int seg, int str, float eps, const float* sc, const float* sh){
    ln_rows<<<dim3((M+3)/4), dim3(256), 0, stream>>>(x, h, M, base, seg, str, eps, sc, sh);
  };
  auto mlp = [&](int M, int base, int seg, int str,
                 const u16* f1t, const float* f1bias, const u16* f2t, const float* f2bias){
    ln(M, base, seg, str, 1e-6f, nullptr, nullptr);
    for (int r0=0; r0<M; r0+=MIDCAP){
      int Mc = (M-r0 < MIDCAP) ? (M-r0) : MIDCAP;
      gemm(1, h,   HIDD, base, r0, seg, str, f1t, f1bias, mid, FFD, 0, 0, IDSEG, 0, Mc, FFD, FFD, HIDD);
      gemm(3, mid, FFD,  0,    0,  IDSEG, 0, f2t, f2bias, x,  HIDD, base, r0, seg, str, Mc, HIDD, HIDD, FFD);
    }
  };

  // ---- input projection + token assembly ----
  {
    tcs(w_in, 0, wt, 320, 384, 384, 1);
    long nin = (long)T_STEPS*NREAL*320;
    cast_arr<<<dim3((unsigned)((nin+255)/256)), dim3(256), 0, stream>>>(in_t, inb, nin);
    set_virt<<<dim3((T_STEPS*NVIRT*HIDD+255)/256), dim3(256), 0, stream>>>(vtr, x);
    gemm(2, inb, 320, 0,0,IDSEG,0, wt, b_in, x, HIDD, 0,0,NREAL,NTOT, T_STEPS*NREAL, 384, 384, 320);
  }

  // ---- 6 layers ----
  for (int j=0; j<6; ++j){
    // per-layer weight transposes: sa sets 0..2, ca sets 0..1 (slice j of each)
    tcs(sa_qw  + (size_t)j*384*384,  6ul*384*384,  wt+LW_SAQ,  384, 384,  384,  3);
    tcs(sa_kvw + (size_t)j*384*768,  6ul*384*768,  wt+LW_SAKV, 384, 768,  768,  3);
    tcs(sa_ow  + (size_t)j*384*384,  6ul*384*384,  wt+LW_SAO,  384, 384,  384,  3);
    tcs(sa_f1w + (size_t)j*384*1536, 6ul*384*1536, wt+LW_SAF1, 384, 1536, 1536, 3);
    tcs(sa_f2w + (size_t)j*1536*384, 6ul*1536*384, wt+LW_SAF2, 1536,384,  384,  3);
    tcs(ca_qw  + (size_t)j*384*384,  6ul*384*384,  wt+LW_CAQ,  384, 384,  384,  2);
    tcs(ca_kvw + (size_t)j*384*768,  6ul*384*768,  wt+LW_CAKV, 384, 768,  768,  2);
    tcs(ca_ow  + (size_t)j*384*384,  6ul*384*384,  wt+LW_CAO,  384, 384,  384,  2);
    tcs(ca_f1w + (size_t)j*384*1536, 6ul*384*1536, wt+LW_CAF1, 384, 1536, 1536, 2);
    tcs(ca_f2w + (size_t)j*1536*384, 6ul*1536*384, wt+LW_CAF2, 1536,384,  384,  2);

    // ===== self over time (all tokens), kv chunked by 2 track groups =====
    {
      int sl = 0*6 + j;
      ln(ROWS_ALL, 0, IDSEG, 0, 1e-6f, nullptr, nullptr);
      gemm(0, h, HIDD, 0,0,IDSEG,0, wt+LW_SAQ, sa_qb+sl*384, qb_, HIDD, 0,0,IDSEG,0, ROWS_ALL, 384,384,384);
      for (int g2=0; g2<2; ++g2){
        int n0 = g2*NG;
        gemm(0, h, HIDD, n0,0,NG,NTOT, wt+LW_SAKV, sa_kvb+sl*768, kvb, 768, 0,0,IDSEG,0, T_STEPS*NG, 768,768,384);
        attn_time_g<<<dim3(NG/4, NHEAD), 64, 0, stream>>>(qb_, kvb, h, n0);
      }
      gemm(3, h, HIDD, 0,0,IDSEG,0, wt+LW_SAO, sa_ob+sl*384, x, HIDD, 0,0,IDSEG,0, ROWS_ALL, 384,384,384);
      mlp(ROWS_ALL, 0, IDSEG, 0, wt+LW_SAF1, sa_f1b+sl*1536, wt+LW_SAF2, sa_f2b+sl*384);
    }

    // ===== cross: virt queries <- real context, kv chunked by 2 time halves =====
    {
      int cl = 0*6 + j;
      ln(T_STEPS*NVIRT, NREAL, NVIRT, NTOT, 1e-6f, nullptr, nullptr);
      ln(T_STEPS*NREAL, 0, NREAL, NTOT, 1e-5f, ca_ncw+cl*384, ca_ncb+cl*384);
      gemm(0, h, HIDD, NREAL,0,NVIRT,NTOT, wt+LW_CAQ, ca_qb+cl*384, qb_, HIDD, 0,0,IDSEG,0, T_STEPS*NVIRT, 384,384,384);
      for (int tc=0; tc<T_STEPS; tc+=8){
        gemm(0, h, HIDD, tc*NTOT,0,NREAL,NTOT, wt+LW_CAKV, ca_kvb+cl*768, kvb, 768, 0,0,IDSEG,0, 8*NREAL, 768,768,384);
        attn_cross_vr_g<<<dim3(8, NHEAD), 256, 0, stream>>>(qb_, kvb, h, tc);
      }
      gemm(3, h, HIDD, NREAL,0,NVIRT,NTOT, wt+LW_CAO, ca_ob+cl*384, x, HIDD, NREAL,0,NVIRT,NTOT, T_STEPS*NVIRT, 384,384,384);
      mlp(T_STEPS*NVIRT, NREAL, NVIRT, NTOT, wt+LW_CAF1, ca_f1b+cl*1536, wt+LW_CAF2, ca_f2b+cl*384);
    }

    // ===== self over virt tokens =====
    {
      int sl = 1*6 + j;
      ln(T_STEPS*NVIRT, NREAL, NVIRT, NTOT, 1e-6f, nullptr, nullptr);
      gemm(0, h, HIDD, NREAL,0,NVIRT,NTOT, wt+LW_SAQ+1ul*147456, sa_qb+sl*384, qb_, HIDD, 0,0,IDSEG,0, T_STEPS*NVIRT, 384,384,384);
      gemm(0, h, HIDD, NREAL,0,NVIRT,NTOT, wt+LW_SAKV+1ul*294912, sa_kvb+sl*768, kvb, 768, 0,0,IDSEG,0, T_STEPS*NVIRT, 768,768,384);
      attn_virt<<<dim3(T_STEPS, NHEAD), 64, 0, stream>>>(qb_, kvb, h);
      gemm(3, h, HIDD, NREAL,0,NVIRT,NTOT, wt+LW_SAO+1ul*147456, sa_ob+sl*384, x, HIDD, NREAL,0,NVIRT,NTOT, T_STEPS*NVIRT, 384,384,384);
      mlp(T_STEPS*NVIRT, NREAL, NVIRT, NTOT, wt+LW_SAF1+1ul*589824, sa_f1b+sl*1536, wt+LW_SAF2+1ul*589824, sa_f2b+sl*384);
    }

    // ===== local windowed self over dense tokens, kv chunked by 2 time halves =====
    {
      int sl = 2*6 + j;
      ln(T_STEPS*NDENSE, NSPARSE, NDENSE, NTOT, 1e-6f, nullptr, nullptr);
      gemm(0, h, HIDD, NSPARSE,0,NDENSE,NTOT, wt+LW_SAQ+2ul*147456, sa_qb+sl*384, qb_, HIDD, 0,0,IDSEG,0, T_STEPS*NDENSE, 384,384,384);
      for (int tc=0; tc<T_STEPS; tc+=8){
        gemm(0, h, HIDD, tc*NTOT+NSPARSE,0,NDENSE,NTOT, wt+LW_SAKV+2ul*294912, sa_kvb+sl*768, kvb, 768, 0,0,IDSEG,0, 8*NDENSE, 768,768,384);
        attn_local_g<<<dim3(88, 8, NHEAD), 64, 0, stream>>>(qb_, kvb, h, tc);
      }
      gemm(3, h, HIDD, NSPARSE,0,NDENSE,NTOT, wt+LW_SAO+2ul*147456, sa_ob+sl*384, x, HIDD, NSPARSE,0,NDENSE,NTOT, T_STEPS*NDENSE, 384,384,384);
      mlp(T_STEPS*NDENSE, NSPARSE, NDENSE, NTOT, wt+LW_SAF1+2ul*589824, sa_f1b+sl*1536, wt+LW_SAF2+2ul*589824, sa_f2b+sl*384);
    }

    // ===== cross: real queries <- virt context =====
    {
      int cl = 1*6 + j;
      ln(T_STEPS*NREAL, 0, NREAL, NTOT, 1e-6f, nullptr, nullptr);
      ln(T_STEPS*NVIRT, NREAL, NVIRT, NTOT, 1e-5f, ca_ncw+cl*384, ca_ncb+cl*384);
      gemm(0, h, HIDD, NREAL,0,NVIRT,NTOT, wt+LW_CAKV+1ul*294912, ca_kvb+cl*768, kvb, 768, 0,0,IDSEG,0, T_STEPS*NVIRT, 768,768,384);
      gemm(0, h, HIDD, 0,0,NREAL,NTOT, wt+LW_CAQ+1ul*147456, ca_qb+cl*384, qb_, HIDD, 0,0,IDSEG,0, T_STEPS*NREAL, 384,384,384);
      attn_cross_rv<<<dim3(52, T_STEPS, NHEAD), 64, 0, stream>>>(qb_, kvb, h);
      gemm(3, h, HIDD, 0,0,NREAL,NTOT, wt+LW_CAO+1ul*147456, ca_ob+cl*384, x, HIDD, 0,0,NREAL,NTOT, T_STEPS*NREAL, 384,384,384);
      mlp(T_STEPS*NREAL, 0, NREAL, NTOT, wt+LW_CAF1+1ul*589824, ca_f1b+cl*1536, wt+LW_CAF2+1ul*589824, ca_f2b+cl*384);
    }
  }

  // ---- output projection ----
  tcs(w_out, 0, wt, 384, 130, 256, 1);
  cast_rows<<<dim3((T_STEPS*NREAL+3)/4), dim3(256), 0, stream>>>(x, h, T_STEPS*NREAL, 0, NREAL, NTOT);
  gemm(2, h, HIDD, 0,0,NREAL,NTOT, wt, b_out, d_out, 130, 0,0,IDSEG,0, T_STEPS*NREAL, 130, 256, 384);
}

// Round 4
// 27424.695 us; speedup vs baseline: 1.0434x; 1.0250x over previous
//
#include <hip/hip_runtime.h>

typedef unsigned short u16;

#define T_STEPS 16
#define NREAL   3328
#define NVIRT   64
#define NTOT    3392
#define HIDD    384
#define FFD     1536
#define NSPARSE 256
#define NDENSE  3072
#define ROWS_ALL (T_STEPS*NTOT)   /* 54272 */
#define NHEAD   8
#define ATT_SCALE 0.14433756729740643f
#define IDSEG   (1<<30)
#define MIDCAP  13568
#define NG      1696              /* track-group size for time attn */

using bf16x8 = __attribute__((ext_vector_type(8))) short;
using f32x4  = __attribute__((ext_vector_type(4))) float;

// ---------------- device helpers ----------------
__device__ __forceinline__ u16 f2b(float f){
  unsigned u = __float_as_uint(f);
  return (u16)((u + 0x7fffu + ((u>>16)&1u)) >> 16);
}
__device__ __forceinline__ void unpack8(uint4 u, float* f){
  f[0]=__uint_as_float(u.x<<16); f[1]=__uint_as_float(u.x&0xffff0000u);
  f[2]=__uint_as_float(u.y<<16); f[3]=__uint_as_float(u.y&0xffff0000u);
  f[4]=__uint_as_float(u.z<<16); f[5]=__uint_as_float(u.z&0xffff0000u);
  f[6]=__uint_as_float(u.w<<16); f[7]=__uint_as_float(u.w&0xffff0000u);
}
__device__ __forceinline__ void load48f(const u16* p, float* f){
#pragma unroll
  for (int c=0;c<6;c++){ uint4 u = *(const uint4*)(p + c*8); unpack8(u, f+c*8); }
}
__device__ __forceinline__ float dot48(const float* q, const u16* p){
  float s = 0.f;
#pragma unroll
  for (int c=0;c<6;c++){
    uint4 u = *(const uint4*)(p + c*8); float kf[8]; unpack8(u,kf);
#pragma unroll
    for (int d=0;d<8;d++) s += q[c*8+d]*kf[d];
  }
  return s;
}
__device__ __forceinline__ void attn_upd(float s, const u16* vp, float& m, float& l, float* acc){
  float mn = fmaxf(m, s);
  float corr = __expf(m - mn);
  float w = __expf(s - mn);
  l = l*corr + w;
#pragma unroll
  for (int c=0;c<6;c++){
    uint4 u = *(const uint4*)(vp + c*8); float vf[8]; unpack8(u,vf);
#pragma unroll
    for (int d=0;d<8;d++){ acc[c*8+d] = acc[c*8+d]*corr + w*vf[d]; }
  }
  m = mn;
}
__device__ __forceinline__ void store48(u16* p, const float* a, float inv){
#pragma unroll
  for (int c=0;c<6;c++){
    uint4 o;
    o.x = (unsigned)f2b(a[c*8+0]*inv) | ((unsigned)f2b(a[c*8+1]*inv)<<16);
    o.y = (unsigned)f2b(a[c*8+2]*inv) | ((unsigned)f2b(a[c*8+3]*inv)<<16);
    o.z = (unsigned)f2b(a[c*8+4]*inv) | ((unsigned)f2b(a[c*8+5]*inv)<<16);
    o.w = (unsigned)f2b(a[c*8+6]*inv) | ((unsigned)f2b(a[c*8+7]*inv)<<16);
    *(uint4*)(p + c*8) = o;
  }
}

// async global->LDS, 16 bytes per lane; lds dest must be wave-uniform base (lane*16 auto)
__device__ __forceinline__ void gload16(const u16* g, u16* l){
  __builtin_amdgcn_global_load_lds((const __attribute__((address_space(1))) void*)g,
                                   (__attribute__((address_space(3))) void*)l, 16, 0, 0);
}

// ---------------- GEMM: C[M,N] = A[M,K](bf16) @ Bt[Npad,K]^T (bf16) + bias ----------------
// Row maps: global_row = base + ((r+rofs)/seg)*str + (r+rofs)%seg
// 2-phase double-buffered K-loop (T3-minimum): STAGE(t+1) issued before compute(t),
// one barrier per K-step; stage latency hides under ds_read+MFMA.
template<int OUTF32, int RES, int GELU>
__global__ __launch_bounds__(256) void gemm_mfma(
    const u16* __restrict__ A, int ldA, int aBase, int aRofs, int aSeg, int aStr,
    const u16* __restrict__ Bt, const float* __restrict__ bias,
    void* __restrict__ C, int ldC, int cBase, int cRofs, int cSeg, int cStr,
    int N, int K)
{
  __shared__ __align__(16) u16 As[2*128*32];
  __shared__ __align__(16) u16 Bs[2*128*32];
  __shared__ int mapA[128];
  __shared__ int mapC[128];
  int tid = threadIdx.x;
  int bm = blockIdx.x, bn = blockIdx.y;
  if (tid < 128){
    int r = bm*128 + tid + aRofs;
    mapA[tid] = aBase + (r/aSeg)*aStr + r%aSeg;
  } else {
    int t2 = tid - 128;
    int r = bm*128 + t2 + cRofs;
    mapC[t2] = cBase + (r/cSeg)*cStr + r%cSeg;
  }
  __syncthreads();

  int wid = tid>>6, lane = tid&63;
  // staging: wave wid owns rows [wid*32, wid*32+32) of both tiles.
  // lane i covers row (i>>2), 16B col chunk (i&3) — linear LDS order.
  int srow = (wid<<5) + (lane>>2);
  int scol = (lane&3)<<3;
  const u16* aSrc0 = A + (long)mapA[srow]*ldA + scol;
  const u16* aSrc1 = A + (long)mapA[srow+16]*ldA + scol;
  long nb0 = (long)bn*128;
  const u16* bSrc0 = Bt + (nb0 + srow)*(long)K + scol;
  const u16* bSrc1 = Bt + (nb0 + srow + 16)*(long)K + scol;
  int aOff0 = (wid<<5)*32;           // wave-uniform LDS elem offsets
  int aOff1 = ((wid<<5)+16)*32;

  int wrow = (wid>>1)<<6, wcol = (wid&1)<<6;
  int lr = lane&15, kq = lane>>4;
  f32x4 acc[4][4] = {};

  // prologue: stage step 0 into buffer 0, drain
  gload16(aSrc0, As + aOff0);
  gload16(aSrc1, As + aOff1);
  gload16(bSrc0, Bs + aOff0);
  gload16(bSrc1, Bs + aOff1);
  __syncthreads();

  int nst = K>>5;
  int cur = 0;
  for (int t=0; t<nst; ++t){
    if (t+1 < nst){                 // stage next K-step into other buffer
      int k0 = (t+1)<<5;
      int bo = (cur^1)*(128*32);
      gload16(aSrc0 + k0, As + bo + aOff0);
      gload16(aSrc1 + k0, As + bo + aOff1);
      gload16(bSrc0 + k0, Bs + bo + aOff0);
      gload16(bSrc1 + k0, Bs + bo + aOff1);
    }
    int bo = cur*(128*32);
    bf16x8 af[4], bfr[4];
#pragma unroll
    for (int mm=0;mm<4;mm++) af[mm]  = *(const bf16x8*)(As + bo + (wrow + mm*16 + lr)*32 + kq*8);
#pragma unroll
    for (int nn=0;nn<4;nn++) bfr[nn] = *(const bf16x8*)(Bs + bo + (wcol + nn*16 + lr)*32 + kq*8);
#pragma unroll
    for (int mm=0;mm<4;mm++){
#pragma unroll
      for (int nn=0;nn<4;nn++){
        acc[mm][nn] = __builtin_amdgcn_mfma_f32_16x16x32_bf16(af[mm], bfr[nn], acc[mm][nn], 0,0,0);
      }
    }
    __syncthreads();   // drains next-stage vmcnt + guards LDS reuse; one barrier per step
    cur ^= 1;
  }
#pragma unroll
  for (int nn=0;nn<4;nn++){
    int col = (int)nb0 + wcol + nn*16 + lr;
    if (col < N){
      float bv = bias[col];
#pragma unroll
      for (int mm=0;mm<4;mm++){
#pragma unroll
        for (int jj=0;jj<4;jj++){
          int rt = wrow + mm*16 + kq*4 + jj;
          float v = acc[mm][nn][jj] + bv;
          if (GELU){
            float x3 = v*v*v;
            v = 0.5f*v*(1.f + tanhf(0.7978845608028654f*(v + 0.044715f*x3)));
          }
          long off = (long)mapC[rt]*ldC + col;
          if (OUTF32){
            float* Cf = (float*)C;
            float r2 = v;
            if (RES) r2 += Cf[off];
            Cf[off] = r2;
          } else {
            ((u16*)C)[off] = f2b(v);
          }
        }
      }
    }
  }
}

// ---------------- LayerNorm over 384, segmented rows, bf16 out, optional affine ----------------
__global__ __launch_bounds__(256) void ln_rows(
    const float* __restrict__ X, u16* __restrict__ H,
    int M, int base, int seg, int str, float eps,
    const float* __restrict__ sc, const float* __restrict__ sh)
{
  int wid = threadIdx.x>>6, lane = threadIdx.x&63;
  int r = blockIdx.x*4 + wid;
  if (r >= M) return;
  long g = base + (long)(r/seg)*str + r%seg;
  const float* xp = X + g*HIDD;
  float v[6]; float s=0.f, ss=0.f;
#pragma unroll
  for (int p=0;p<6;p++){ v[p] = xp[lane + 64*p]; s += v[p]; ss += v[p]*v[p]; }
#pragma unroll
  for (int o=32;o>=1;o>>=1){ s += __shfl_xor(s,o); ss += __shfl_xor(ss,o); }
  float mean = s*(1.f/384.f);
  float var  = ss*(1.f/384.f) - mean*mean;
  float rstd = rsqrtf(var + eps);
  u16* hp = H + g*HIDD;
#pragma unroll
  for (int p=0;p<6;p++){
    int c = lane + 64*p;
    float y = (v[p]-mean)*rstd;
    if (sc) y = y*sc[c] + sh[c];
    hp[c] = f2b(y);
  }
}

// cast f32 rows -> bf16 rows (segmented)
__global__ __launch_bounds__(256) void cast_rows(
    const float* __restrict__ X, u16* __restrict__ H, int M, int base, int seg, int str)
{
  int wid = threadIdx.x>>6, lane = threadIdx.x&63;
  int r = blockIdx.x*4 + wid;
  if (r >= M) return;
  long g = base + (long)(r/seg)*str + r%seg;
  const float* xp = X + g*HIDD;
  u16* hp = H + g*HIDD;
#pragma unroll
  for (int p=0;p<6;p++){ int c = lane + 64*p; hp[c] = f2b(xp[c]); }
}

// elementwise f32 -> bf16
__global__ void cast_arr(const float* __restrict__ S, u16* __restrict__ D, long n){
  long i = (long)blockIdx.x*256 + threadIdx.x;
  if (i < n) D[i] = f2b(S[i]);
}

// broadcast virtual tracks into x
__global__ void set_virt(const float* __restrict__ vtr, float* __restrict__ X){
  int idx = blockIdx.x*256 + threadIdx.x;
  if (idx >= T_STEPS*NVIRT*HIDD) return;
  int c = idx % HIDD;
  int i = (idx / HIDD) % NVIRT;
  int t = idx / (HIDD*NVIRT);
  X[((long)t*NTOT + NREAL + i)*HIDD + c] = vtr[i*HIDD + c];
}

// transpose-cast weights: src + mat*srcStride = [K][N] f32 -> dst[mat] = [Npad][K] bf16 (zero pad)
__global__ void transpose_cast(const float* __restrict__ src, long srcStride,
                               u16* __restrict__ dst, int K, int N, int Npad)
{
  __shared__ float t[32][33];
  int mat = blockIdx.z;
  const float* S = src + (long)mat*srcStride;
  u16* D = dst + (long)mat*Npad*K;
  int k0 = blockIdx.x*32, n0 = blockIdx.y*32;
  int tx = threadIdx.x, ty = threadIdx.y;
#pragma unroll
  for (int yy=0; yy<4; yy++){
    int k = k0+ty+8*yy, n = n0+tx;
    t[ty+8*yy][tx] = (k<K && n<N) ? S[(long)k*N+n] : 0.f;
  }
  __syncthreads();
#pragma unroll
  for (int yy=0; yy<4; yy++){
    int n = n0+ty+8*yy, k = k0+tx;
    if (n<Npad && k<K) D[(long)n*K+k] = f2b(t[tx][ty+8*yy]);
  }
}

// ---------------- attention kernels ----------------
// time self-attn over track group [n0, n0+NG). Q,O global rows; KV compact [t*NG+nl].
// grid (NG/4, 8), block 64
__global__ __launch_bounds__(64) void attn_time_g(const u16* __restrict__ Q, const u16* __restrict__ KV,
                                                  u16* __restrict__ O, int n0){
  int lane = threadIdx.x;
  int nl = blockIdx.x*4 + (lane>>4);
  int tq = lane&15;
  int hh = blockIdx.y;
  long qrow = (long)tq*NTOT + n0 + nl;
  float qv[48]; load48f(Q + qrow*HIDD + hh*48, qv);
  float m=-3e38f, l=0.f, acc[48];
#pragma unroll
  for (int d=0;d<48;d++) acc[d]=0.f;
  for (int tk=0;tk<T_STEPS;tk++){
    long kr = (long)tk*NG + nl;
    const u16* kp = KV + kr*768 + hh*48;
    float s = dot48(qv, kp)*ATT_SCALE;
    attn_upd(s, kp+384, m, l, acc);
  }
  store48(O + qrow*HIDD + hh*48, acc, 1.f/l);
}

// virt self-attn. Q compact [t*64+i], KV compact, O global. grid (16, 8), block 64
__global__ __launch_bounds__(64) void attn_virt(const u16* __restrict__ Q, const u16* __restrict__ KV, u16* __restrict__ O){
  int lane = threadIdx.x;
  int t = blockIdx.x, hh = blockIdx.y;
  long qr = (long)t*NVIRT + lane;
  float qv[48]; load48f(Q + qr*HIDD + hh*48, qv);
  float m=-3e38f, l=0.f, acc[48];
#pragma unroll
  for (int d=0;d<48;d++) acc[d]=0.f;
  for (int tk=0;tk<NVIRT;tk++){
    long kr = (long)t*NVIRT + tk;
    const u16* kp = KV + kr*768 + hh*48;
    float s = dot48(qv, kp)*ATT_SCALE;
    attn_upd(s, kp+384, m, l, acc);
  }
  long orow = (long)t*NTOT + NREAL + lane;
  store48(O + orow*HIDD + hh*48, acc, 1.f/l);
}

// cross: virt queries over real keys, time chunk starting t0 (8 steps).
// Q compact [t*64+i] (all t), KV compact [tl*3328+n], O global. grid (8, 8), block 256
__global__ __launch_bounds__(256) void attn_cross_vr_g(const u16* __restrict__ Q, const u16* __restrict__ KV,
                                                       u16* __restrict__ O, int t0){
  __shared__ float pm[4][64];
  __shared__ float pl[4][64];
  __shared__ float pacc[4][64][48];
  int tl = blockIdx.x, hh = blockIdx.y;
  int w = threadIdx.x>>6, lane = threadIdx.x&63;
  long qr = (long)(t0+tl)*NVIRT + lane;
  float qv[48]; load48f(Q + qr*HIDD + hh*48, qv);
  float m=-3e38f, l=0.f, acc[48];
#pragma unroll
  for (int d=0;d<48;d++) acc[d]=0.f;
  int k0 = w*832, k1 = k0+832;
  for (int mk=k0; mk<k1; ++mk){
    long kr = (long)tl*NREAL + mk;
    const u16* kp = KV + kr*768 + hh*48;
    float s = dot48(qv, kp)*ATT_SCALE;
    attn_upd(s, kp+384, m, l, acc);
  }
  pm[w][lane]=m; pl[w][lane]=l;
#pragma unroll
  for (int d=0;d<48;d++) pacc[w][lane][d]=acc[d];
  __syncthreads();
  if (w==0){
    float M2 = pm[0][lane];
#pragma unroll
    for (int ww=1;ww<4;ww++) M2 = fmaxf(M2, pm[ww][lane]);
    float L=0.f; float out[48];
#pragma unroll
    for (int d=0;d<48;d++) out[d]=0.f;
#pragma unroll
    for (int ww=0;ww<4;ww++){
      float c = __expf(pm[ww][lane]-M2);
      L += pl[ww][lane]*c;
#pragma unroll
      for (int d=0;d<48;d++) out[d] += pacc[ww][lane][d]*c;
    }
    long orow = (long)(t0+tl)*NTOT + NREAL + lane;
    store48(O + orow*HIDD + hh*48, out, 1.f/L);
  }
}

// cross: real queries over virt keys. Q compact [t*3328+n], KV compact [t*64+i], O global.
// grid (52, 16, 8), block 64
__global__ __launch_bounds__(64) void attn_cross_rv(const u16* __restrict__ Q, const u16* __restrict__ KV, u16* __restrict__ O){
  int lane = threadIdx.x;
  int t = blockIdx.y, hh = blockIdx.z;
  int n = blockIdx.x*64 + lane;
  long qr = (long)t*NREAL + n;
  float qv[48]; load48f(Q + qr*HIDD + hh*48, qv);
  float m=-3e38f, l=0.f, acc[48];
#pragma unroll
  for (int d=0;d<48;d++) acc[d]=0.f;
  for (int tk=0;tk<NVIRT;tk++){
    long kr = (long)t*NVIRT + tk;
    const u16* kp = KV + kr*768 + hh*48;
    float s = dot48(qv, kp)*ATT_SCALE;
    attn_upd(s, kp+384, m, l, acc);
  }
  long orow = (long)t*NTOT + n;
  store48(O + orow*HIDD + hh*48, acc, 1.f/l);
}

// local 6x6 windowed self-attn over dense tokens, time chunk t0 (8 steps).
// Q compact [t*3072+d], KV compact [tl*3072+d], O global. grid (88, 8, 8), block 64
__global__ __launch_bounds__(64) void attn_local_g(const u16* __restrict__ Q, const u16* __restrict__ KV,
                                                   u16* __restrict__ O, int t0){
  int lane = threadIdx.x;
  if (lane >= 36) return;
  int wh = blockIdx.x/11, ww = blockIdx.x%11;
  int i = lane/6, jc = lane%6;
  int jmax = (ww==10) ? 4 : 6;
  if (jc >= jmax) return;
  int tl = blockIdx.y, hh = blockIdx.z;
  int d0 = (wh*6+i)*64 + ww*6+jc;
  long qr = (long)(t0+tl)*NDENSE + d0;
  float qv[48]; load48f(Q + qr*HIDD + hh*48, qv);
  float m=-3e38f, l=0.f, acc[48];
#pragma unroll
  for (int dd=0;dd<48;dd++) acc[dd]=0.f;
  for (int i2=0;i2<6;i2++){
    for (int j2=0;j2<jmax;j2++){
      long kr = (long)tl*NDENSE + (wh*6+i2)*64 + ww*6+j2;
      const u16* kp = KV + kr*768 + hh*48;
      float s = dot48(qv, kp)*ATT_SCALE;
      attn_upd(s, kp+384, m, l, acc);
    }
  }
  long orow = (long)(t0+tl)*NTOT + NSPARSE + d0;
  store48(O + orow*HIDD + hh*48, acc, 1.f/l);
}

// ---------------- host ----------------
// per-layer transposed-weight arena offsets (elements)
static const size_t LW_SAQ  = 0;                       // 3 * 147456
static const size_t LW_SAKV = LW_SAQ  + 3ul*147456;    // 3 * 294912
static const size_t LW_SAO  = LW_SAKV + 3ul*294912;    // 3 * 147456
static const size_t LW_SAF1 = LW_SAO  + 3ul*147456;    // 3 * 589824
static const size_t LW_SAF2 = LW_SAF1 + 3ul*589824;    // 3 * 589824
static const size_t LW_CAQ  = LW_SAF2 + 3ul*589824;    // 2 * 147456
static const size_t LW_CAKV = LW_CAQ  + 2ul*147456;    // 2 * 294912
static const size_t LW_CAO  = LW_CAKV + 2ul*294912;    // 2 * 147456
static const size_t LW_CAF1 = LW_CAO  + 2ul*147456;    // 2 * 589824
static const size_t LW_CAF2 = LW_CAF1 + 2ul*589824;    // 2 * 589824
static const size_t LW_TOTAL= LW_CAF2 + 2ul*589824;    // 8,847,360 elems

extern "C" void kernel_launch(void* const* d_in, const int* in_sizes, int n_in,
                              void* d_out, int out_size, void* d_ws, size_t ws_size,
                              hipStream_t stream)
{
  const float* in_t   = (const float*)d_in[0];
  const float* w_in   = (const float*)d_in[2];
  const float* b_in   = (const float*)d_in[3];
  const float* w_out  = (const float*)d_in[4];
  const float* b_out  = (const float*)d_in[5];
  const float* vtr    = (const float*)d_in[6];
  const float* sa_qw  = (const float*)d_in[7];
  const float* sa_qb  = (const float*)d_in[8];
  const float* sa_kvw = (const float*)d_in[9];
  const float* sa_kvb = (const float*)d_in[10];
  const float* sa_ow  = (const float*)d_in[11];
  const float* sa_ob  = (const float*)d_in[12];
  const float* sa_f1w = (const float*)d_in[13];
  const float* sa_f1b = (const float*)d_in[14];
  const float* sa_f2w = (const float*)d_in[15];
  const float* sa_f2b = (const float*)d_in[16];
  const float* ca_qw  = (const float*)d_in[17];
  const float* ca_qb  = (const float*)d_in[18];
  const float* ca_kvw = (const float*)d_in[19];
  const float* ca_kvb = (const float*)d_in[20];
  const float* ca_ow  = (const float*)d_in[21];
  const float* ca_ob  = (const float*)d_in[22];
  const float* ca_f1w = (const float*)d_in[23];
  const float* ca_f1b = (const float*)d_in[24];
  const float* ca_f2w = (const float*)d_in[25];
  const float* ca_f2b = (const float*)d_in[26];
  const float* ca_ncw = (const float*)d_in[27];
  const float* ca_ncb = (const float*)d_in[28];

  char* ws = (char*)d_ws;
  size_t off = 0;
  auto alloc = [&](size_t bytes)->void*{
    void* p = ws + off;
    off += (bytes + 255) & ~(size_t)255;
    return p;
  };
  // ~226 MB total
  float* x  = (float*)alloc((size_t)ROWS_ALL*HIDD*4);   // 83.4 MB  f32 residual stream
  u16* h    = (u16*)alloc((size_t)ROWS_ALL*HIDD*2);     // 41.7 MB  ln output; doubles as attn-O
  u16* qb_  = (u16*)alloc((size_t)ROWS_ALL*HIDD*2);     // 41.7 MB  Q buffer; doubles as MLP mid
  u16* kvb  = (u16*)alloc((size_t)T_STEPS*NG*768*2);    // 41.7 MB  KV (chunked); doubles as input cast
  u16* wt   = (u16*)alloc(LW_TOTAL*2);                  // 17.7 MB  per-layer transposed weights
  u16* mid  = qb_;                                      // MIDCAP*1536*2 == qb_ bytes exactly
  u16* inb  = kvb;                                      // 34.1 MB <= kvb bytes

  auto tcs = [&](const float* src, long srcStride, u16* dst, int K, int Nn, int Npad, int nmat){
    dim3 g((K+31)/32, (Npad+31)/32, nmat), b(32,8);
    transpose_cast<<<g,b,0,stream>>>(src, srcStride, dst, K, Nn, Npad);
  };

  // mode 0=bf16 out, 1=bf16+gelu, 2=f32 out, 3=f32+residual
  auto gemm = [&](int mode, const u16* A, int ldA, int aBase, int aRofs, int aSeg, int aStr,
                  const u16* Bt, const float* bias,
                  void* C, int ldC, int cBase, int cRofs, int cSeg, int cStr,
                  int M, int Nn, int Npad, int K){
    dim3 g(M/128, Npad/128), b(256);
    if (mode==0)      gemm_mfma<0,0,0><<<g,b,0,stream>>>(A,ldA,aBase,aRofs,aSeg,aStr,Bt,bias,C,ldC,cBase,cRofs,cSeg,cStr,Nn,K);
    else if (mode==1) gemm_mfma<0,0,1><<<g,b,0,stream>>>(A,ldA,aBase,aRofs,aSeg,aStr,Bt,bias,C,ldC,cBase,cRofs,cSeg,cStr,Nn,K);
    else if (mode==2) gemm_mfma<1,0,0><<<g,b,0,stream>>>(A,ldA,aBase,aRofs,aSeg,aStr,Bt,bias,C,ldC,cBase,cRofs,cSeg,cStr,Nn,K);
    else              gemm_mfma<1,1,0><<<g,b,0,stream>>>(A,ldA,aBase,aRofs,aSeg,aStr,Bt,bias,C,ldC,cBase,cRofs,cSeg,cStr,Nn,K);
  };
  auto ln = [&](int M, int base, int seg, int str, float eps, const float* sc, const float* sh){
    ln_rows<<<dim3((M+3)/4), dim3(256), 0, stream>>>(x, h, M, base, seg, str, eps, sc, sh);
  };
  auto mlp = [&](int M, int base, int seg, int str,
                 const u16* f1t, const float* f1bias, const u16* f2t, const float* f2bias){
    ln(M, base, seg, str, 1e-6f, nullptr, nullptr);
    for (int r0=0; r0<M; r0+=MIDCAP){
      int Mc = (M-r0 < MIDCAP) ? (M-r0) : MIDCAP;
      gemm(1, h,   HIDD, base, r0, seg, str, f1t, f1bias, mid, FFD, 0, 0, IDSEG, 0, Mc, FFD, FFD, HIDD);
      gemm(3, mid, FFD,  0,    0,  IDSEG, 0, f2t, f2bias, x,  HIDD, base, r0, seg, str, Mc, HIDD, HIDD, FFD);
    }
  };

  // ---- input projection + token assembly ----
  {
    tcs(w_in, 0, wt, 320, 384, 384, 1);
    long nin = (long)T_STEPS*NREAL*320;
    cast_arr<<<dim3((unsigned)((nin+255)/256)), dim3(256), 0, stream>>>(in_t, inb, nin);
    set_virt<<<dim3((T_STEPS*NVIRT*HIDD+255)/256), dim3(256), 0, stream>>>(vtr, x);
    gemm(2, inb, 320, 0,0,IDSEG,0, wt, b_in, x, HIDD, 0,0,NREAL,NTOT, T_STEPS*NREAL, 384, 384, 320);
  }

  // ---- 6 layers ----
  for (int j=0; j<6; ++j){
    // per-layer weight transposes: sa sets 0..2, ca sets 0..1 (slice j of each)
    tcs(sa_qw  + (size_t)j*384*384,  6ul*384*384,  wt+LW_SAQ,  384, 384,  384,  3);
    tcs(sa_kvw + (size_t)j*384*768,  6ul*384*768,  wt+LW_SAKV, 384, 768,  768,  3);
    tcs(sa_ow  + (size_t)j*384*384,  6ul*384*384,  wt+LW_SAO,  384, 384,  384,  3);
    tcs(sa_f1w + (size_t)j*384*1536, 6ul*384*1536, wt+LW_SAF1, 384, 1536, 1536, 3);
    tcs(sa_f2w + (size_t)j*1536*384, 6ul*1536*384, wt+LW_SAF2, 1536,384,  384,  3);
    tcs(ca_qw  + (size_t)j*384*384,  6ul*384*384,  wt+LW_CAQ,  384, 384,  384,  2);
    tcs(ca_kvw + (size_t)j*384*768,  6ul*384*768,  wt+LW_CAKV, 384, 768,  768,  2);
    tcs(ca_ow  + (size_t)j*384*384,  6ul*384*384,  wt+LW_CAO,  384, 384,  384,  2);
    tcs(ca_f1w + (size_t)j*384*1536, 6ul*384*1536, wt+LW_CAF1, 384, 1536, 1536, 2);
    tcs(ca_f2w + (size_t)j*1536*384, 6ul*1536*384, wt+LW_CAF2, 1536,384,  384,  2);

    // ===== self over time (all tokens), kv chunked by 2 track groups =====
    {
      int sl = 0*6 + j;
      ln(ROWS_ALL, 0, IDSEG, 0, 1e-6f, nullptr, nullptr);
      gemm(0, h, HIDD, 0,0,IDSEG,0, wt+LW_SAQ, sa_qb+sl*384, qb_, HIDD, 0,0,IDSEG,0, ROWS_ALL, 384,384,384);
      for (int g2=0; g2<2; ++g2){
        int n0 = g2*NG;
        gemm(0, h, HIDD, n0,0,NG,NTOT, wt+LW_SAKV, sa_kvb+sl*768, kvb, 768, 0,0,IDSEG,0, T_STEPS*NG, 768,768,384);
        attn_time_g<<<dim3(NG/4, NHEAD), 64, 0, stream>>>(qb_, kvb, h, n0);
      }
      gemm(3, h, HIDD, 0,0,IDSEG,0, wt+LW_SAO, sa_ob+sl*384, x, HIDD, 0,0,IDSEG,0, ROWS_ALL, 384,384,384);
      mlp(ROWS_ALL, 0, IDSEG, 0, wt+LW_SAF1, sa_f1b+sl*1536, wt+LW_SAF2, sa_f2b+sl*384);
    }

    // ===== cross: virt queries <- real context, kv chunked by 2 time halves =====
    {
      int cl = 0*6 + j;
      ln(T_STEPS*NVIRT, NREAL, NVIRT, NTOT, 1e-6f, nullptr, nullptr);
      ln(T_STEPS*NREAL, 0, NREAL, NTOT, 1e-5f, ca_ncw+cl*384, ca_ncb+cl*384);
      gemm(0, h, HIDD, NREAL,0,NVIRT,NTOT, wt+LW_CAQ, ca_qb+cl*384, qb_, HIDD, 0,0,IDSEG,0, T_STEPS*NVIRT, 384,384,384);
      for (int tc=0; tc<T_STEPS; tc+=8){
        gemm(0, h, HIDD, tc*NTOT,0,NREAL,NTOT, wt+LW_CAKV, ca_kvb+cl*768, kvb, 768, 0,0,IDSEG,0, 8*NREAL, 768,768,384);
        attn_cross_vr_g<<<dim3(8, NHEAD), 256, 0, stream>>>(qb_, kvb, h, tc);
      }
      gemm(3, h, HIDD, NREAL,0,NVIRT,NTOT, wt+LW_CAO, ca_ob+cl*384, x, HIDD, NREAL,0,NVIRT,NTOT, T_STEPS*NVIRT, 384,384,384);
      mlp(T_STEPS*NVIRT, NREAL, NVIRT, NTOT, wt+LW_CAF1, ca_f1b+cl*1536, wt+LW_CAF2, ca_f2b+cl*384);
    }

    // ===== self over virt tokens =====
    {
      int sl = 1*6 + j;
      ln(T_STEPS*NVIRT, NREAL, NVIRT, NTOT, 1e-6f, nullptr, nullptr);
      gemm(0, h, HIDD, NREAL,0,NVIRT,NTOT, wt+LW_SAQ+1ul*147456, sa_qb+sl*384, qb_, HIDD, 0,0,IDSEG,0, T_STEPS*NVIRT, 384,384,384);
      gemm(0, h, HIDD, NREAL,0,NVIRT,NTOT, wt+LW_SAKV+1ul*294912, sa_kvb+sl*768, kvb, 768, 0,0,IDSEG,0, T_STEPS*NVIRT, 768,768,384);
      attn_virt<<<dim3(T_STEPS, NHEAD), 64, 0, stream>>>(qb_, kvb, h);
      gemm(3, h, HIDD, NREAL,0,NVIRT,NTOT, wt+LW_SAO+1ul*147456, sa_ob+sl*384, x, HIDD, NREAL,0,NVIRT,NTOT, T_STEPS*NVIRT, 384,384,384);
      mlp(T_STEPS*NVIRT, NREAL, NVIRT, NTOT, wt+LW_SAF1+1ul*589824, sa_f1b+sl*1536, wt+LW_SAF2+1ul*589824, sa_f2b+sl*384);
    }

    // ===== local windowed self over dense tokens, kv chunked by 2 time halves =====
    {
      int sl = 2*6 + j;
      ln(T_STEPS*NDENSE, NSPARSE, NDENSE, NTOT, 1e-6f, nullptr, nullptr);
      gemm(0, h, HIDD, NSPARSE,0,NDENSE,NTOT, wt+LW_SAQ+2ul*147456, sa_qb+sl*384, qb_, HIDD, 0,0,IDSEG,0, T_STEPS*NDENSE, 384,384,384);
      for (int tc=0; tc<T_STEPS; tc+=8){
        gemm(0, h, HIDD, tc*NTOT+NSPARSE,0,NDENSE,NTOT, wt+LW_SAKV+2ul*294912, sa_kvb+sl*768, kvb, 768, 0,0,IDSEG,0, 8*NDENSE, 768,768,384);
        attn_local_g<<<dim3(88, 8, NHEAD), 64, 0, stream>>>(qb_, kvb, h, tc);
      }
      gemm(3, h, HIDD, NSPARSE,0,NDENSE,NTOT, wt+LW_SAO+2ul*147456, sa_ob+sl*384, x, HIDD, NSPARSE,0,NDENSE,NTOT, T_STEPS*NDENSE, 384,384,384);
      mlp(T_STEPS*NDENSE, NSPARSE, NDENSE, NTOT, wt+LW_SAF1+2ul*589824, sa_f1b+sl*1536, wt+LW_SAF2+2ul*589824, sa_f2b+sl*384);
    }

    // ===== cross: real queries <- virt context =====
    {
      int cl = 1*6 + j;
      ln(T_STEPS*NREAL, 0, NREAL, NTOT, 1e-6f, nullptr, nullptr);
      ln(T_STEPS*NVIRT, NREAL, NVIRT, NTOT, 1e-5f, ca_ncw+cl*384, ca_ncb+cl*384);
      gemm(0, h, HIDD, NREAL,0,NVIRT,NTOT, wt+LW_CAKV+1ul*294912, ca_kvb+cl*768, kvb, 768, 0,0,IDSEG,0, T_STEPS*NVIRT, 768,768,384);
      gemm(0, h, HIDD, 0,0,NREAL,NTOT, wt+LW_CAQ+1ul*147456, ca_qb+cl*384, qb_, HIDD, 0,0,IDSEG,0, T_STEPS*NREAL, 384,384,384);
      attn_cross_rv<<<dim3(52, T_STEPS, NHEAD), 64, 0, stream>>>(qb_, kvb, h);
      gemm(3, h, HIDD, 0,0,NREAL,NTOT, wt+LW_CAO+1ul*147456, ca_ob+cl*384, x, HIDD, 0,0,NREAL,NTOT, T_STEPS*NREAL, 384,384,384);
      mlp(T_STEPS*NREAL, 0, NREAL, NTOT, wt+LW_CAF1+1ul*589824, ca_f1b+cl*1536, wt+LW_CAF2+1ul*589824, ca_f2b+cl*384);
    }
  }

  // ---- output projection ----
  tcs(w_out, 0, wt, 384, 130, 256, 1);
  cast_rows<<<dim3((T_STEPS*NREAL+3)/4), dim3(256), 0, stream>>>(x, h, T_STEPS*NREAL, 0, NREAL, NTOT);
  gemm(2, h, HIDD, 0,0,NREAL,NTOT, wt, b_out, d_out, 130, 0,0,IDSEG,0, T_STEPS*NREAL, 130, 256, 384);
}

// Round 5
// 27385.068 us; speedup vs baseline: 1.0450x; 1.0014x over previous
//
#include <hip/hip_runtime.h>

typedef unsigned short u16;

#define T_STEPS 16
#define NREAL   3328
#define NVIRT   64
#define NTOT    3392
#define HIDD    384
#define FFD     1536
#define NSPARSE 256
#define NDENSE  3072
#define ROWS_ALL (T_STEPS*NTOT)   /* 54272 */
#define NHEAD   8
#define ATT_SCALE 0.14433756729740643f
#define IDSEG   (1<<30)
#define MIDCAP  13568
#define NG      1696              /* track-group size for time attn */

using bf16x8 = __attribute__((ext_vector_type(8))) short;
using f32x4  = __attribute__((ext_vector_type(4))) float;

// ---------------- device helpers ----------------
__device__ __forceinline__ u16 f2b(float f){
  unsigned u = __float_as_uint(f);
  return (u16)((u + 0x7fffu + ((u>>16)&1u)) >> 16);
}
__device__ __forceinline__ void unpack8(uint4 u, float* f){
  f[0]=__uint_as_float(u.x<<16); f[1]=__uint_as_float(u.x&0xffff0000u);
  f[2]=__uint_as_float(u.y<<16); f[3]=__uint_as_float(u.y&0xffff0000u);
  f[4]=__uint_as_float(u.z<<16); f[5]=__uint_as_float(u.z&0xffff0000u);
  f[6]=__uint_as_float(u.w<<16); f[7]=__uint_as_float(u.w&0xffff0000u);
}
__device__ __forceinline__ void load48f(const u16* p, float* f){
#pragma unroll
  for (int c=0;c<6;c++){ uint4 u = *(const uint4*)(p + c*8); unpack8(u, f+c*8); }
}
__device__ __forceinline__ float dot48(const float* q, const u16* p){
  float s = 0.f;
#pragma unroll
  for (int c=0;c<6;c++){
    uint4 u = *(const uint4*)(p + c*8); float kf[8]; unpack8(u,kf);
#pragma unroll
    for (int d=0;d<8;d++) s += q[c*8+d]*kf[d];
  }
  return s;
}
__device__ __forceinline__ void attn_upd(float s, const u16* vp, float& m, float& l, float* acc){
  float mn = fmaxf(m, s);
  float corr = __expf(m - mn);
  float w = __expf(s - mn);
  l = l*corr + w;
#pragma unroll
  for (int c=0;c<6;c++){
    uint4 u = *(const uint4*)(vp + c*8); float vf[8]; unpack8(u,vf);
#pragma unroll
    for (int d=0;d<8;d++){ acc[c*8+d] = acc[c*8+d]*corr + w*vf[d]; }
  }
  m = mn;
}
__device__ __forceinline__ void store48(u16* p, const float* a, float inv){
#pragma unroll
  for (int c=0;c<6;c++){
    uint4 o;
    o.x = (unsigned)f2b(a[c*8+0]*inv) | ((unsigned)f2b(a[c*8+1]*inv)<<16);
    o.y = (unsigned)f2b(a[c*8+2]*inv) | ((unsigned)f2b(a[c*8+3]*inv)<<16);
    o.z = (unsigned)f2b(a[c*8+4]*inv) | ((unsigned)f2b(a[c*8+5]*inv)<<16);
    o.w = (unsigned)f2b(a[c*8+6]*inv) | ((unsigned)f2b(a[c*8+7]*inv)<<16);
    *(uint4*)(p + c*8) = o;
  }
}

// async global->LDS, 16 bytes per lane; lds dest must be wave-uniform base (lane*16 auto)
__device__ __forceinline__ void gload16(const u16* g, u16* l){
  __builtin_amdgcn_global_load_lds((const __attribute__((address_space(1))) void*)g,
                                   (__attribute__((address_space(3))) void*)l, 16, 0, 0);
}

// ---------------- GEMM: C[M,N] = A[M,K](bf16) @ Bt[Npad,K]^T (bf16) + bias ----------------
// Row maps: global_row = base + ((r+rofs)/seg)*str + (r+rofs)%seg
// Depth-3 pipeline (T3+T4): 3 LDS buffers, counted s_waitcnt vmcnt(4) + raw s_barrier,
// one barrier per K-step; stage(t) has ~2 compute phases to land (loads in flight across barriers).
template<int OUTF32, int RES, int GELU>
__global__ __launch_bounds__(256) void gemm_mfma(
    const u16* __restrict__ A, int ldA, int aBase, int aRofs, int aSeg, int aStr,
    const u16* __restrict__ Bt, const float* __restrict__ bias,
    void* __restrict__ C, int ldC, int cBase, int cRofs, int cSeg, int cStr,
    int N, int K)
{
  __shared__ __align__(16) u16 As[3*128*32];
  __shared__ __align__(16) u16 Bs[3*128*32];
  __shared__ int mapA[128];
  __shared__ int mapC[128];
  int tid = threadIdx.x;
  int bm = blockIdx.x, bn = blockIdx.y;
  if (tid < 128){
    int r = bm*128 + tid + aRofs;
    mapA[tid] = aBase + (r/aSeg)*aStr + r%aSeg;
  } else {
    int t2 = tid - 128;
    int r = bm*128 + t2 + cRofs;
    mapC[t2] = cBase + (r/cSeg)*cStr + r%cSeg;
  }
  __syncthreads();

  int wid = tid>>6, lane = tid&63;
  // staging: wave wid owns rows [wid*32, wid*32+32) of both tiles.
  // lane i covers row (i>>2), 16B col chunk (i&3) — linear LDS order.
  int srow = (wid<<5) + (lane>>2);
  int scol = (lane&3)<<3;
  const u16* aSrc0 = A + (long)mapA[srow]*ldA + scol;
  const u16* aSrc1 = A + (long)mapA[srow+16]*ldA + scol;
  long nb0 = (long)bn*128;
  const u16* bSrc0 = Bt + (nb0 + srow)*(long)K + scol;
  const u16* bSrc1 = Bt + (nb0 + srow + 16)*(long)K + scol;
  int off0 = (wid<<5)*32;           // wave-uniform LDS elem offsets
  int off1 = ((wid<<5)+16)*32;

  int wrow = (wid>>1)<<6, wcol = (wid&1)<<6;
  int lr = lane&15, kq = lane>>4;
  f32x4 acc[4][4] = {};

  auto stage = [&](int t, int buf){
    int k0 = t<<5, bo = buf*(128*32);
    gload16(aSrc0 + k0, As + bo + off0);
    gload16(aSrc1 + k0, As + bo + off1);
    gload16(bSrc0 + k0, Bs + bo + off0);
    gload16(bSrc1 + k0, Bs + bo + off1);
  };

  int nst = K>>5;      // >= 10 for all our shapes
  stage(0, 0);
  stage(1, 1);
  int cb = 0;          // buffer holding K-step t
  for (int t=0; t<nst; ++t){
    // oldest outstanding stage (t) must have landed; newer (t+1) stays in flight.
    if (t < nst-1) { asm volatile("s_waitcnt vmcnt(4)" ::: "memory"); }
    else           { asm volatile("s_waitcnt vmcnt(0)" ::: "memory"); }
    __builtin_amdgcn_s_barrier();            // raw barrier: no vmcnt drain
    __builtin_amdgcn_sched_barrier(0);       // pin: nothing crosses the barrier
    if (t+2 < nst){
      int nb = cb+2; if (nb>=3) nb-=3;       // buffer last read at t-1: safe post-barrier
      stage(t+2, nb);
    }
    int bo = cb*(128*32);
    bf16x8 af[4], bfr[4];
#pragma unroll
    for (int mm=0;mm<4;mm++) af[mm]  = *(const bf16x8*)(As + bo + (wrow + mm*16 + lr)*32 + kq*8);
#pragma unroll
    for (int nn=0;nn<4;nn++) bfr[nn] = *(const bf16x8*)(Bs + bo + (wcol + nn*16 + lr)*32 + kq*8);
#pragma unroll
    for (int mm=0;mm<4;mm++){
#pragma unroll
      for (int nn=0;nn<4;nn++){
        acc[mm][nn] = __builtin_amdgcn_mfma_f32_16x16x32_bf16(af[mm], bfr[nn], acc[mm][nn], 0,0,0);
      }
    }
    cb++; if (cb==3) cb=0;
  }
  __builtin_amdgcn_sched_barrier(0);
#pragma unroll
  for (int nn=0;nn<4;nn++){
    int col = (int)nb0 + wcol + nn*16 + lr;
    if (col < N){
      float bv = bias[col];
#pragma unroll
      for (int mm=0;mm<4;mm++){
#pragma unroll
        for (int jj=0;jj<4;jj++){
          int rt = wrow + mm*16 + kq*4 + jj;
          float v = acc[mm][nn][jj] + bv;
          if (GELU){
            float x3 = v*v*v;
            v = 0.5f*v*(1.f + tanhf(0.7978845608028654f*(v + 0.044715f*x3)));
          }
          long off = (long)mapC[rt]*ldC + col;
          if (OUTF32){
            float* Cf = (float*)C;
            float r2 = v;
            if (RES) r2 += Cf[off];
            Cf[off] = r2;
          } else {
            ((u16*)C)[off] = f2b(v);
          }
        }
      }
    }
  }
}

// ---------------- LayerNorm over 384, segmented rows, bf16 out, optional affine ----------------
__global__ __launch_bounds__(256) void ln_rows(
    const float* __restrict__ X, u16* __restrict__ H,
    int M, int base, int seg, int str, float eps,
    const float* __restrict__ sc, const float* __restrict__ sh)
{
  int wid = threadIdx.x>>6, lane = threadIdx.x&63;
  int r = blockIdx.x*4 + wid;
  if (r >= M) return;
  long g = base + (long)(r/seg)*str + r%seg;
  const float* xp = X + g*HIDD;
  float v[6]; float s=0.f, ss=0.f;
#pragma unroll
  for (int p=0;p<6;p++){ v[p] = xp[lane + 64*p]; s += v[p]; ss += v[p]*v[p]; }
#pragma unroll
  for (int o=32;o>=1;o>>=1){ s += __shfl_xor(s,o); ss += __shfl_xor(ss,o); }
  float mean = s*(1.f/384.f);
  float var  = ss*(1.f/384.f) - mean*mean;
  float rstd = rsqrtf(var + eps);
  u16* hp = H + g*HIDD;
#pragma unroll
  for (int p=0;p<6;p++){
    int c = lane + 64*p;
    float y = (v[p]-mean)*rstd;
    if (sc) y = y*sc[c] + sh[c];
    hp[c] = f2b(y);
  }
}

// cast f32 rows -> bf16 rows (segmented)
__global__ __launch_bounds__(256) void cast_rows(
    const float* __restrict__ X, u16* __restrict__ H, int M, int base, int seg, int str)
{
  int wid = threadIdx.x>>6, lane = threadIdx.x&63;
  int r = blockIdx.x*4 + wid;
  if (r >= M) return;
  long g = base + (long)(r/seg)*str + r%seg;
  const float* xp = X + g*HIDD;
  u16* hp = H + g*HIDD;
#pragma unroll
  for (int p=0;p<6;p++){ int c = lane + 64*p; hp[c] = f2b(xp[c]); }
}

// elementwise f32 -> bf16
__global__ void cast_arr(const float* __restrict__ S, u16* __restrict__ D, long n){
  long i = (long)blockIdx.x*256 + threadIdx.x;
  if (i < n) D[i] = f2b(S[i]);
}

// broadcast virtual tracks into x
__global__ void set_virt(const float* __restrict__ vtr, float* __restrict__ X){
  int idx = blockIdx.x*256 + threadIdx.x;
  if (idx >= T_STEPS*NVIRT*HIDD) return;
  int c = idx % HIDD;
  int i = (idx / HIDD) % NVIRT;
  int t = idx / (HIDD*NVIRT);
  X[((long)t*NTOT + NREAL + i)*HIDD + c] = vtr[i*HIDD + c];
}

// transpose-cast weights: src + mat*srcStride = [K][N] f32 -> dst[mat] = [Npad][K] bf16 (zero pad)
__global__ void transpose_cast(const float* __restrict__ src, long srcStride,
                               u16* __restrict__ dst, int K, int N, int Npad)
{
  __shared__ float t[32][33];
  int mat = blockIdx.z;
  const float* S = src + (long)mat*srcStride;
  u16* D = dst + (long)mat*Npad*K;
  int k0 = blockIdx.x*32, n0 = blockIdx.y*32;
  int tx = threadIdx.x, ty = threadIdx.y;
#pragma unroll
  for (int yy=0; yy<4; yy++){
    int k = k0+ty+8*yy, n = n0+tx;
    t[ty+8*yy][tx] = (k<K && n<N) ? S[(long)k*N+n] : 0.f;
  }
  __syncthreads();
#pragma unroll
  for (int yy=0; yy<4; yy++){
    int n = n0+ty+8*yy, k = k0+tx;
    if (n<Npad && k<K) D[(long)n*K+k] = f2b(t[tx][ty+8*yy]);
  }
}

// ---------------- attention kernels ----------------
// time self-attn over track group [n0, n0+NG). Q,O global rows; KV compact [t*NG+nl].
// grid (NG/4, 8), block 64
__global__ __launch_bounds__(64) void attn_time_g(const u16* __restrict__ Q, const u16* __restrict__ KV,
                                                  u16* __restrict__ O, int n0){
  int lane = threadIdx.x;
  int nl = blockIdx.x*4 + (lane>>4);
  int tq = lane&15;
  int hh = blockIdx.y;
  long qrow = (long)tq*NTOT + n0 + nl;
  float qv[48]; load48f(Q + qrow*HIDD + hh*48, qv);
  float m=-3e38f, l=0.f, acc[48];
#pragma unroll
  for (int d=0;d<48;d++) acc[d]=0.f;
  for (int tk=0;tk<T_STEPS;tk++){
    long kr = (long)tk*NG + nl;
    const u16* kp = KV + kr*768 + hh*48;
    float s = dot48(qv, kp)*ATT_SCALE;
    attn_upd(s, kp+384, m, l, acc);
  }
  store48(O + qrow*HIDD + hh*48, acc, 1.f/l);
}

// virt self-attn. Q compact [t*64+i], KV compact, O global. grid (16, 8), block 64
__global__ __launch_bounds__(64) void attn_virt(const u16* __restrict__ Q, const u16* __restrict__ KV, u16* __restrict__ O){
  int lane = threadIdx.x;
  int t = blockIdx.x, hh = blockIdx.y;
  long qr = (long)t*NVIRT + lane;
  float qv[48]; load48f(Q + qr*HIDD + hh*48, qv);
  float m=-3e38f, l=0.f, acc[48];
#pragma unroll
  for (int d=0;d<48;d++) acc[d]=0.f;
  for (int tk=0;tk<NVIRT;tk++){
    long kr = (long)t*NVIRT + tk;
    const u16* kp = KV + kr*768 + hh*48;
    float s = dot48(qv, kp)*ATT_SCALE;
    attn_upd(s, kp+384, m, l, acc);
  }
  long orow = (long)t*NTOT + NREAL + lane;
  store48(O + orow*HIDD + hh*48, acc, 1.f/l);
}

// cross: virt queries over real keys, time chunk starting t0 (8 steps).
// Q compact [t*64+i] (all t), KV compact [tl*3328+n], O global. grid (8, 8), block 256
__global__ __launch_bounds__(256) void attn_cross_vr_g(const u16* __restrict__ Q, const u16* __restrict__ KV,
                                                       u16* __restrict__ O, int t0){
  __shared__ float pm[4][64];
  __shared__ float pl[4][64];
  __shared__ float pacc[4][64][48];
  int tl = blockIdx.x, hh = blockIdx.y;
  int w = threadIdx.x>>6, lane = threadIdx.x&63;
  long qr = (long)(t0+tl)*NVIRT + lane;
  float qv[48]; load48f(Q + qr*HIDD + hh*48, qv);
  float m=-3e38f, l=0.f, acc[48];
#pragma unroll
  for (int d=0;d<48;d++) acc[d]=0.f;
  int k0 = w*832, k1 = k0+832;
  for (int mk=k0; mk<k1; ++mk){
    long kr = (long)tl*NREAL + mk;
    const u16* kp = KV + kr*768 + hh*48;
    float s = dot48(qv, kp)*ATT_SCALE;
    attn_upd(s, kp+384, m, l, acc);
  }
  pm[w][lane]=m; pl[w][lane]=l;
#pragma unroll
  for (int d=0;d<48;d++) pacc[w][lane][d]=acc[d];
  __syncthreads();
  if (w==0){
    float M2 = pm[0][lane];
#pragma unroll
    for (int ww=1;ww<4;ww++) M2 = fmaxf(M2, pm[ww][lane]);
    float L=0.f; float out[48];
#pragma unroll
    for (int d=0;d<48;d++) out[d]=0.f;
#pragma unroll
    for (int ww=0;ww<4;ww++){
      float c = __expf(pm[ww][lane]-M2);
      L += pl[ww][lane]*c;
#pragma unroll
      for (int d=0;d<48;d++) out[d] += pacc[ww][lane][d]*c;
    }
    long orow = (long)(t0+tl)*NTOT + NREAL + lane;
    store48(O + orow*HIDD + hh*48, out, 1.f/L);
  }
}

// cross: real queries over virt keys. Q compact [t*3328+n], KV compact [t*64+i], O global.
// grid (52, 16, 8), block 64
__global__ __launch_bounds__(64) void attn_cross_rv(const u16* __restrict__ Q, const u16* __restrict__ KV, u16* __restrict__ O){
  int lane = threadIdx.x;
  int t = blockIdx.y, hh = blockIdx.z;
  int n = blockIdx.x*64 + lane;
  long qr = (long)t*NREAL + n;
  float qv[48]; load48f(Q + qr*HIDD + hh*48, qv);
  float m=-3e38f, l=0.f, acc[48];
#pragma unroll
  for (int d=0;d<48;d++) acc[d]=0.f;
  for (int tk=0;tk<NVIRT;tk++){
    long kr = (long)t*NVIRT + tk;
    const u16* kp = KV + kr*768 + hh*48;
    float s = dot48(qv, kp)*ATT_SCALE;
    attn_upd(s, kp+384, m, l, acc);
  }
  long orow = (long)t*NTOT + n;
  store48(O + orow*HIDD + hh*48, acc, 1.f/l);
}

// local 6x6 windowed self-attn over dense tokens, time chunk t0 (8 steps).
// Q compact [t*3072+d], KV compact [tl*3072+d], O global. grid (88, 8, 8), block 64
__global__ __launch_bounds__(64) void attn_local_g(const u16* __restrict__ Q, const u16* __restrict__ KV,
                                                   u16* __restrict__ O, int t0){
  int lane = threadIdx.x;
  if (lane >= 36) return;
  int wh = blockIdx.x/11, ww = blockIdx.x%11;
  int i = lane/6, jc = lane%6;
  int jmax = (ww==10) ? 4 : 6;
  if (jc >= jmax) return;
  int tl = blockIdx.y, hh = blockIdx.z;
  int d0 = (wh*6+i)*64 + ww*6+jc;
  long qr = (long)(t0+tl)*NDENSE + d0;
  float qv[48]; load48f(Q + qr*HIDD + hh*48, qv);
  float m=-3e38f, l=0.f, acc[48];
#pragma unroll
  for (int dd=0;dd<48;dd++) acc[dd]=0.f;
  for (int i2=0;i2<6;i2++){
    for (int j2=0;j2<jmax;j2++){
      long kr = (long)tl*NDENSE + (wh*6+i2)*64 + ww*6+j2;
      const u16* kp = KV + kr*768 + hh*48;
      float s = dot48(qv, kp)*ATT_SCALE;
      attn_upd(s, kp+384, m, l, acc);
    }
  }
  long orow = (long)(t0+tl)*NTOT + NSPARSE + d0;
  store48(O + orow*HIDD + hh*48, acc, 1.f/l);
}

// ---------------- host ----------------
// per-layer transposed-weight arena offsets (elements)
static const size_t LW_SAQ  = 0;                       // 3 * 147456
static const size_t LW_SAKV = LW_SAQ  + 3ul*147456;    // 3 * 294912
static const size_t LW_SAO  = LW_SAKV + 3ul*294912;    // 3 * 147456
static const size_t LW_SAF1 = LW_SAO  + 3ul*147456;    // 3 * 589824
static const size_t LW_SAF2 = LW_SAF1 + 3ul*589824;    // 3 * 589824
static const size_t LW_CAQ  = LW_SAF2 + 3ul*589824;    // 2 * 147456
static const size_t LW_CAKV = LW_CAQ  + 2ul*147456;    // 2 * 294912
static const size_t LW_CAO  = LW_CAKV + 2ul*294912;    // 2 * 147456
static const size_t LW_CAF1 = LW_CAO  + 2ul*147456;    // 2 * 589824
static const size_t LW_CAF2 = LW_CAF1 + 2ul*589824;    // 2 * 589824
static const size_t LW_TOTAL= LW_CAF2 + 2ul*589824;    // 8,847,360 elems

extern "C" void kernel_launch(void* const* d_in, const int* in_sizes, int n_in,
                              void* d_out, int out_size, void* d_ws, size_t ws_size,
                              hipStream_t stream)
{
  const float* in_t   = (const float*)d_in[0];
  const float* w_in   = (const float*)d_in[2];
  const float* b_in   = (const float*)d_in[3];
  const float* w_out  = (const float*)d_in[4];
  const float* b_out  = (const float*)d_in[5];
  const float* vtr    = (const float*)d_in[6];
  const float* sa_qw  = (const float*)d_in[7];
  const float* sa_qb  = (const float*)d_in[8];
  const float* sa_kvw = (const float*)d_in[9];
  const float* sa_kvb = (const float*)d_in[10];
  const float* sa_ow  = (const float*)d_in[11];
  const float* sa_ob  = (const float*)d_in[12];
  const float* sa_f1w = (const float*)d_in[13];
  const float* sa_f1b = (const float*)d_in[14];
  const float* sa_f2w = (const float*)d_in[15];
  const float* sa_f2b = (const float*)d_in[16];
  const float* ca_qw  = (const float*)d_in[17];
  const float* ca_qb  = (const float*)d_in[18];
  const float* ca_kvw = (const float*)d_in[19];
  const float* ca_kvb = (const float*)d_in[20];
  const float* ca_ow  = (const float*)d_in[21];
  const float* ca_ob  = (const float*)d_in[22];
  const float* ca_f1w = (const float*)d_in[23];
  const float* ca_f1b = (const float*)d_in[24];
  const float* ca_f2w = (const float*)d_in[25];
  const float* ca_f2b = (const float*)d_in[26];
  const float* ca_ncw = (const float*)d_in[27];
  const float* ca_ncb = (const float*)d_in[28];

  char* ws = (char*)d_ws;
  size_t off = 0;
  auto alloc = [&](size_t bytes)->void*{
    void* p = ws + off;
    off += (bytes + 255) & ~(size_t)255;
    return p;
  };
  // ~226 MB total
  float* x  = (float*)alloc((size_t)ROWS_ALL*HIDD*4);   // 83.4 MB  f32 residual stream
  u16* h    = (u16*)alloc((size_t)ROWS_ALL*HIDD*2);     // 41.7 MB  ln output; doubles as attn-O
  u16* qb_  = (u16*)alloc((size_t)ROWS_ALL*HIDD*2);     // 41.7 MB  Q buffer; doubles as MLP mid
  u16* kvb  = (u16*)alloc((size_t)T_STEPS*NG*768*2);    // 41.7 MB  KV (chunked); doubles as input cast
  u16* wt   = (u16*)alloc(LW_TOTAL*2);                  // 17.7 MB  per-layer transposed weights
  u16* mid  = qb_;                                      // MIDCAP*1536*2 == qb_ bytes exactly
  u16* inb  = kvb;                                      // 34.1 MB <= kvb bytes

  auto tcs = [&](const float* src, long srcStride, u16* dst, int K, int Nn, int Npad, int nmat){
    dim3 g((K+31)/32, (Npad+31)/32, nmat), b(32,8);
    transpose_cast<<<g,b,0,stream>>>(src, srcStride, dst, K, Nn, Npad);
  };

  // mode 0=bf16 out, 1=bf16+gelu, 2=f32 out, 3=f32+residual
  auto gemm = [&](int mode, const u16* A, int ldA, int aBase, int aRofs, int aSeg, int aStr,
                  const u16* Bt, const float* bias,
                  void* C, int ldC, int cBase, int cRofs, int cSeg, int cStr,
                  int M, int Nn, int Npad, int K){
    dim3 g(M/128, Npad/128), b(256);
    if (mode==0)      gemm_mfma<0,0,0><<<g,b,0,stream>>>(A,ldA,aBase,aRofs,aSeg,aStr,Bt,bias,C,ldC,cBase,cRofs,cSeg,cStr,Nn,K);
    else if (mode==1) gemm_mfma<0,0,1><<<g,b,0,stream>>>(A,ldA,aBase,aRofs,aSeg,aStr,Bt,bias,C,ldC,cBase,cRofs,cSeg,cStr,Nn,K);
    else if (mode==2) gemm_mfma<1,0,0><<<g,b,0,stream>>>(A,ldA,aBase,aRofs,aSeg,aStr,Bt,bias,C,ldC,cBase,cRofs,cSeg,cStr,Nn,K);
    else              gemm_mfma<1,1,0><<<g,b,0,stream>>>(A,ldA,aBase,aRofs,aSeg,aStr,Bt,bias,C,ldC,cBase,cRofs,cSeg,cStr,Nn,K);
  };
  auto ln = [&](int M, int base, int seg, int str, float eps, const float* sc, const float* sh){
    ln_rows<<<dim3((M+3)/4), dim3(256), 0, stream>>>(x, h, M, base, seg, str, eps, sc, sh);
  };
  auto mlp = [&](int M, int base, int seg, int str,
                 const u16* f1t, const float* f1bias, const u16* f2t, const float* f2bias){
    ln(M, base, seg, str, 1e-6f, nullptr, nullptr);
    for (int r0=0; r0<M; r0+=MIDCAP){
      int Mc = (M-r0 < MIDCAP) ? (M-r0) : MIDCAP;
      gemm(1, h,   HIDD, base, r0, seg, str, f1t, f1bias, mid, FFD, 0, 0, IDSEG, 0, Mc, FFD, FFD, HIDD);
      gemm(3, mid, FFD,  0,    0,  IDSEG, 0, f2t, f2bias, x,  HIDD, base, r0, seg, str, Mc, HIDD, HIDD, FFD);
    }
  };

  // ---- input projection + token assembly ----
  {
    tcs(w_in, 0, wt, 320, 384, 384, 1);
    long nin = (long)T_STEPS*NREAL*320;
    cast_arr<<<dim3((unsigned)((nin+255)/256)), dim3(256), 0, stream>>>(in_t, inb, nin);
    set_virt<<<dim3((T_STEPS*NVIRT*HIDD+255)/256), dim3(256), 0, stream>>>(vtr, x);
    gemm(2, inb, 320, 0,0,IDSEG,0, wt, b_in, x, HIDD, 0,0,NREAL,NTOT, T_STEPS*NREAL, 384, 384, 320);
  }

  // ---- 6 layers ----
  for (int j=0; j<6; ++j){
    // per-layer weight transposes: sa sets 0..2, ca sets 0..1 (slice j of each)
    tcs(sa_qw  + (size_t)j*384*384,  6ul*384*384,  wt+LW_SAQ,  384, 384,  384,  3);
    tcs(sa_kvw + (size_t)j*384*768,  6ul*384*768,  wt+LW_SAKV, 384, 768,  768,  3);
    tcs(sa_ow  + (size_t)j*384*384,  6ul*384*384,  wt+LW_SAO,  384, 384,  384,  3);
    tcs(sa_f1w + (size_t)j*384*1536, 6ul*384*1536, wt+LW_SAF1, 384, 1536, 1536, 3);
    tcs(sa_f2w + (size_t)j*1536*384, 6ul*1536*384, wt+LW_SAF2, 1536,384,  384,  3);
    tcs(ca_qw  + (size_t)j*384*384,  6ul*384*384,  wt+LW_CAQ,  384, 384,  384,  2);
    tcs(ca_kvw + (size_t)j*384*768,  6ul*384*768,  wt+LW_CAKV, 384, 768,  768,  2);
    tcs(ca_ow  + (size_t)j*384*384,  6ul*384*384,  wt+LW_CAO,  384, 384,  384,  2);
    tcs(ca_f1w + (size_t)j*384*1536, 6ul*384*1536, wt+LW_CAF1, 384, 1536, 1536, 2);
    tcs(ca_f2w + (size_t)j*1536*384, 6ul*1536*384, wt+LW_CAF2, 1536,384,  384,  2);

    // ===== self over time (all tokens), kv chunked by 2 track groups =====
    {
      int sl = 0*6 + j;
      ln(ROWS_ALL, 0, IDSEG, 0, 1e-6f, nullptr, nullptr);
      gemm(0, h, HIDD, 0,0,IDSEG,0, wt+LW_SAQ, sa_qb+sl*384, qb_, HIDD, 0,0,IDSEG,0, ROWS_ALL, 384,384,384);
      for (int g2=0; g2<2; ++g2){
        int n0 = g2*NG;
        gemm(0, h, HIDD, n0,0,NG,NTOT, wt+LW_SAKV, sa_kvb+sl*768, kvb, 768, 0,0,IDSEG,0, T_STEPS*NG, 768,768,384);
        attn_time_g<<<dim3(NG/4, NHEAD), 64, 0, stream>>>(qb_, kvb, h, n0);
      }
      gemm(3, h, HIDD, 0,0,IDSEG,0, wt+LW_SAO, sa_ob+sl*384, x, HIDD, 0,0,IDSEG,0, ROWS_ALL, 384,384,384);
      mlp(ROWS_ALL, 0, IDSEG, 0, wt+LW_SAF1, sa_f1b+sl*1536, wt+LW_SAF2, sa_f2b+sl*384);
    }

    // ===== cross: virt queries <- real context, kv chunked by 2 time halves =====
    {
      int cl = 0*6 + j;
      ln(T_STEPS*NVIRT, NREAL, NVIRT, NTOT, 1e-6f, nullptr, nullptr);
      ln(T_STEPS*NREAL, 0, NREAL, NTOT, 1e-5f, ca_ncw+cl*384, ca_ncb+cl*384);
      gemm(0, h, HIDD, NREAL,0,NVIRT,NTOT, wt+LW_CAQ, ca_qb+cl*384, qb_, HIDD, 0,0,IDSEG,0, T_STEPS*NVIRT, 384,384,384);
      for (int tc=0; tc<T_STEPS; tc+=8){
        gemm(0, h, HIDD, tc*NTOT,0,NREAL,NTOT, wt+LW_CAKV, ca_kvb+cl*768, kvb, 768, 0,0,IDSEG,0, 8*NREAL, 768,768,384);
        attn_cross_vr_g<<<dim3(8, NHEAD), 256, 0, stream>>>(qb_, kvb, h, tc);
      }
      gemm(3, h, HIDD, NREAL,0,NVIRT,NTOT, wt+LW_CAO, ca_ob+cl*384, x, HIDD, NREAL,0,NVIRT,NTOT, T_STEPS*NVIRT, 384,384,384);
      mlp(T_STEPS*NVIRT, NREAL, NVIRT, NTOT, wt+LW_CAF1, ca_f1b+cl*1536, wt+LW_CAF2, ca_f2b+cl*384);
    }

    // ===== self over virt tokens =====
    {
      int sl = 1*6 + j;
      ln(T_STEPS*NVIRT, NREAL, NVIRT, NTOT, 1e-6f, nullptr, nullptr);
      gemm(0, h, HIDD, NREAL,0,NVIRT,NTOT, wt+LW_SAQ+1ul*147456, sa_qb+sl*384, qb_, HIDD, 0,0,IDSEG,0, T_STEPS*NVIRT, 384,384,384);
      gemm(0, h, HIDD, NREAL,0,NVIRT,NTOT, wt+LW_SAKV+1ul*294912, sa_kvb+sl*768, kvb, 768, 0,0,IDSEG,0, T_STEPS*NVIRT, 768,768,384);
      attn_virt<<<dim3(T_STEPS, NHEAD), 64, 0, stream>>>(qb_, kvb, h);
      gemm(3, h, HIDD, NREAL,0,NVIRT,NTOT, wt+LW_SAO+1ul*147456, sa_ob+sl*384, x, HIDD, NREAL,0,NVIRT,NTOT, T_STEPS*NVIRT, 384,384,384);
      mlp(T_STEPS*NVIRT, NREAL, NVIRT, NTOT, wt+LW_SAF1+1ul*589824, sa_f1b+sl*1536, wt+LW_SAF2+1ul*589824, sa_f2b+sl*384);
    }

    // ===== local windowed self over dense tokens, kv chunked by 2 time halves =====
    {
      int sl = 2*6 + j;
      ln(T_STEPS*NDENSE, NSPARSE, NDENSE, NTOT, 1e-6f, nullptr, nullptr);
      gemm(0, h, HIDD, NSPARSE,0,NDENSE,NTOT, wt+LW_SAQ+2ul*147456, sa_qb+sl*384, qb_, HIDD, 0,0,IDSEG,0, T_STEPS*NDENSE, 384,384,384);
      for (int tc=0; tc<T_STEPS; tc+=8){
        gemm(0, h, HIDD, tc*NTOT+NSPARSE,0,NDENSE,NTOT, wt+LW_SAKV+2ul*294912, sa_kvb+sl*768, kvb, 768, 0,0,IDSEG,0, 8*NDENSE, 768,768,384);
        attn_local_g<<<dim3(88, 8, NHEAD), 64, 0, stream>>>(qb_, kvb, h, tc);
      }
      gemm(3, h, HIDD, NSPARSE,0,NDENSE,NTOT, wt+LW_SAO+2ul*147456, sa_ob+sl*384, x, HIDD, NSPARSE,0,NDENSE,NTOT, T_STEPS*NDENSE, 384,384,384);
      mlp(T_STEPS*NDENSE, NSPARSE, NDENSE, NTOT, wt+LW_SAF1+2ul*589824, sa_f1b+sl*1536, wt+LW_SAF2+2ul*589824, sa_f2b+sl*384);
    }

    // ===== cross: real queries <- virt context =====
    {
      int cl = 1*6 + j;
      ln(T_STEPS*NREAL, 0, NREAL, NTOT, 1e-6f, nullptr, nullptr);
      ln(T_STEPS*NVIRT, NREAL, NVIRT, NTOT, 1e-5f, ca_ncw+cl*384, ca_ncb+cl*384);
      gemm(0, h, HIDD, NREAL,0,NVIRT,NTOT, wt+LW_CAKV+1ul*294912, ca_kvb+cl*768, kvb, 768, 0,0,IDSEG,0, T_STEPS*NVIRT, 768,768,384);
      gemm(0, h, HIDD, 0,0,NREAL,NTOT, wt+LW_CAQ+1ul*147456, ca_qb+cl*384, qb_, HIDD, 0,0,IDSEG,0, T_STEPS*NREAL, 384,384,384);
      attn_cross_rv<<<dim3(52, T_STEPS, NHEAD), 64, 0, stream>>>(qb_, kvb, h);
      gemm(3, h, HIDD, 0,0,NREAL,NTOT, wt+LW_CAO+1ul*147456, ca_ob+cl*384, x, HIDD, 0,0,NREAL,NTOT, T_STEPS*NREAL, 384,384,384);
      mlp(T_STEPS*NREAL, 0, NREAL, NTOT, wt+LW_CAF1+1ul*589824, ca_f1b+cl*1536, wt+LW_CAF2+1ul*589824, ca_f2b+cl*384);
    }
  }

  // ---- output projection ----
  tcs(w_out, 0, wt, 384, 130, 256, 1);
  cast_rows<<<dim3((T_STEPS*NREAL+3)/4), dim3(256), 0, stream>>>(x, h, T_STEPS*NREAL, 0, NREAL, NTOT);
  gemm(2, h, HIDD, 0,0,NREAL,NTOT, wt, b_out, d_out, 130, 0,0,IDSEG,0, T_STEPS*NREAL, 130, 256, 384);
}